// Round 3
// baseline (4620.971 us; speedup 1.0000x reference)
//
#include <hip/hip_runtime.h>
#include <cstdint>
#include <cstddef>

#define DIMC     512
#define D_INNER  1024
#define HEADDIM  128
#define NHEADS   8
#define D_STATE  128
#define CONV_DIM 1280
#define D_IN_PROJ 2312
#define BSZ      4
#define LSEQ     4096
#define BLTOT    (BSZ*LSEQ)   // 16384
#define NC       8            // chunks
#define CLEN     (LSEQ/NC)    // 512
#define TS       4            // t-steps per LDS staging round

// ---------------- K1: in_proj GEMM ----------------
__global__ __launch_bounds__(256) void k1_inproj(
    const float* __restrict__ x, const float* __restrict__ W,
    float* __restrict__ zbuf, float* __restrict__ xbc, float* __restrict__ dtb)
{
    __shared__ float As[32][68];
    __shared__ float Bs[32][68];
    const int tx = threadIdx.x, ty = threadIdx.y;
    const int tid = ty * 16 + tx;
    const int n0 = blockIdx.x * 64;
    const int m0 = blockIdx.y * 64;
    const int b  = m0 >> 12;
    const int l0 = m0 & 4095;

    float c[4][4] = {};
    const int am = tid & 63, ak = tid >> 6;
    const int bk = tid & 31, bn = tid >> 5;

    for (int kb = 0; kb < DIMC; kb += 32) {
        #pragma unroll
        for (int kk = 0; kk < 32; kk += 4) {
            As[ak + kk][am] = x[((size_t)(b * DIMC + kb + ak + kk) << 12) + l0 + am];
        }
        #pragma unroll
        for (int nn = 0; nn < 8; ++nn) {
            int n = bn * 8 + nn;
            int e = n0 + n;
            Bs[bk][n] = (e < D_IN_PROJ) ? W[(size_t)e * DIMC + kb + bk] : 0.f;
        }
        __syncthreads();
        #pragma unroll
        for (int kk = 0; kk < 32; ++kk) {
            float4 a4 = *(const float4*)&As[kk][ty * 4];
            float4 b4 = *(const float4*)&Bs[kk][tx * 4];
            float av_[4] = {a4.x, a4.y, a4.z, a4.w};
            float bv_[4] = {b4.x, b4.y, b4.z, b4.w};
            #pragma unroll
            for (int i = 0; i < 4; ++i)
                #pragma unroll
                for (int j = 0; j < 4; ++j)
                    c[i][j] = fmaf(av_[i], bv_[j], c[i][j]);
        }
        __syncthreads();
    }
    #pragma unroll
    for (int i = 0; i < 4; ++i) {
        int m = m0 + ty * 4 + i;
        #pragma unroll
        for (int j = 0; j < 4; ++j) {
            int e = n0 + tx * 4 + j;
            float v = c[i][j];
            if (e < D_INNER)                  zbuf[(size_t)m * D_INNER + e] = v;
            else if (e < D_INNER + CONV_DIM)  xbc[(size_t)m * CONV_DIM + (e - D_INNER)] = v;
            else if (e < D_IN_PROJ)           dtb[(size_t)m * NHEADS + (e - (D_INNER + CONV_DIM))] = v;
        }
    }
}

// ---------------- K2: softplus(dt + bias), dA ----------------
__global__ __launch_bounds__(256) void k2_dt(
    const float* __restrict__ dtb, const float* __restrict__ dt_bias,
    const float* __restrict__ A_log, float* __restrict__ dtp, float* __restrict__ dAb)
{
    int idx = blockIdx.x * 256 + threadIdx.x;
    if (idx >= BLTOT * NHEADS) return;
    int h = idx & 7;
    float v = dtb[idx] + dt_bias[h];
    float sp = (v > 20.f) ? v : log1pf(expf(v));
    dtp[idx] = sp;
    dAb[idx] = expf(sp * (-expf(A_log[h])));
}

// ---------------- K3: causal depthwise conv(4) + SiLU ----------------
__global__ __launch_bounds__(256) void k3_conv(
    const float* __restrict__ xbc, const float* __restrict__ cw,
    const float* __restrict__ cb, float* __restrict__ xbcc)
{
    int idx = blockIdx.x * 256 + threadIdx.x;
    int c = idx % CONV_DIM;
    int m = idx / CONV_DIM;
    int l = m & 4095;
    float acc = cb[c];
    #pragma unroll
    for (int j = 0; j < 4; ++j) {
        if (l - j >= 0)
            acc = fmaf(xbc[(size_t)(m - j) * CONV_DIM + c], cw[c * 4 + (3 - j)], acc);
    }
    xbcc[idx] = acc / (1.f + expf(-acc));
}

// ---------------- K4a: chunked SSM scan (local), LDS y staging ----------------
__global__ __launch_bounds__(256, 6) void k4a_scan(
    const float* __restrict__ xbcc, const float* __restrict__ dtp,
    const float* __restrict__ dAb, const float* __restrict__ Dp,
    float* __restrict__ ybuf, float* __restrict__ statebuf, float* __restrict__ dcum)
{
    __shared__ float4 sBC[2][TS][64];
    __shared__ float4 sX[2][TS][4];
    __shared__ float  sAD[2][TS][2];
    __shared__ float  sY[32][20];       // 32 t-rows x 16 p (padded)

    const int tid  = threadIdx.x;
    const int lane = tid & 63;
    const int warp = tid >> 6;
    const int pg = blockIdx.x & 7;
    const int c  = (blockIdx.x >> 3) & 7;
    const int h  = (blockIdx.x >> 6) & 7;
    const int b  = blockIdx.x >> 9;
    const int p  = pg * 16 + warp * 4 + (lane & 3);
    const int nq = (lane >> 2) * 2;
    const float Dh = Dp[h];
    const size_t mbase = (size_t)b * LSEQ + c * CLEN;

    const int ld_t = tid >> 6;
    const int ld_q = tid & 63;

    auto stage = [&](int buf, int r) {
        int t0 = r * TS;
        {
            const float* row = xbcc + (mbase + t0 + ld_t) * CONV_DIM;
            sBC[buf][ld_t][ld_q] = *(const float4*)(row + D_INNER + ld_q * 4);
        }
        if (tid < 16) {
            int tl = tid >> 2, j = tid & 3;
            const float* row = xbcc + (mbase + t0 + tl) * CONV_DIM;
            sX[buf][tl][j] = *(const float4*)(row + h * HEADDIM + pg * 16 + j * 4);
        } else if (tid < 24) {
            int tl = (tid - 16) >> 1, k = tid & 1;
            size_t idx = (mbase + t0 + tl) * NHEADS + h;
            sAD[buf][tl][k] = k ? dtp[idx] : dAb[idx];
        }
    };

    stage(0, 0);
    __syncthreads();

    float s0=0.f,s1=0.f,s2=0.f,s3=0.f,s4=0.f,s5=0.f,s6=0.f,s7=0.f;
    float cum = 1.f;
    const bool store_dc = (pg == 0 && tid == 0);
    float* dcp = dcum + (size_t)(b * NHEADS + h) * LSEQ + c * CLEN;

    const int NR = CLEN / TS;
    for (int r = 0; r < NR; ++r) {
        const int buf = r & 1;
        if (r + 1 < NR) stage(buf ^ 1, r + 1);
        #pragma unroll
        for (int tl = 0; tl < TS; ++tl) {
            const float4 b0 = sBC[buf][tl][nq];
            const float4 b1 = sBC[buf][tl][nq + 1];
            const float4 c0 = sBC[buf][tl][32 + nq];
            const float4 c1 = sBC[buf][tl][32 + nq + 1];
            const float xt  = ((const float*)&sX[buf][tl][0])[warp * 4 + (lane & 3)];
            const float dAt = sAD[buf][tl][0];
            const float dtt = sAD[buf][tl][1];

            const float dtx = dtt * xt;
            float y0, y1;
            s0 = fmaf(s0, dAt, dtx * b0.x); y0 = s0 * c0.x;
            s1 = fmaf(s1, dAt, dtx * b0.y); y1 = s1 * c0.y;
            s2 = fmaf(s2, dAt, dtx * b0.z); y0 = fmaf(s2, c0.z, y0);
            s3 = fmaf(s3, dAt, dtx * b0.w); y1 = fmaf(s3, c0.w, y1);
            s4 = fmaf(s4, dAt, dtx * b1.x); y0 = fmaf(s4, c1.x, y0);
            s5 = fmaf(s5, dAt, dtx * b1.y); y1 = fmaf(s5, c1.y, y1);
            s6 = fmaf(s6, dAt, dtx * b1.z); y0 = fmaf(s6, c1.z, y0);
            s7 = fmaf(s7, dAt, dtx * b1.w); y1 = fmaf(s7, c1.w, y1);
            float y = y0 + y1;
            y += __shfl_xor(y, 4);
            y += __shfl_xor(y, 8);
            y += __shfl_xor(y, 16);
            y += __shfl_xor(y, 32);
            cum *= dAt;
            if (store_dc) dcp[r * TS + tl] = cum;
            if (lane < 4) sY[(r * TS + tl) & 31][warp * 4 + lane] = fmaf(Dh, xt, y);
        }
        __syncthreads();
        if ((r & 7) == 7) {
            // flush 32 rows: pure coalesced store (full 64B lines)
            int t0f = (r - 7) * TS;
            if (tid < 128) {
                int fr = tid >> 2, c4 = (tid & 3) * 4;
                float4 v = *(const float4*)&sY[fr][c4];
                *(float4*)(ybuf + (mbase + t0f + fr) * D_INNER + h * HEADDIM + pg * 16 + c4) = v;
            }
            __syncthreads();
        }
    }

    float* sb = statebuf + ((((size_t)(b * NHEADS + h) * NC + c) * HEADDIM + p) * D_STATE + nq * 4);
    *(float4*)sb       = make_float4(s0, s1, s2, s3);
    *(float4*)(sb + 4) = make_float4(s4, s5, s6, s7);
}

// ---------------- K4b: cross-chunk state prefix (in place) ----------------
__global__ __launch_bounds__(256) void k4b_prefix(
    float* __restrict__ statebuf, const float* __restrict__ dcum)
{
    const int bh = blockIdx.x;
    const int tid = threadIdx.x;
    float P[NC];
    #pragma unroll
    for (int c = 0; c < NC; ++c)
        P[c] = dcum[(size_t)bh * LSEQ + c * CLEN + (CLEN - 1)];
    float* base = statebuf + (size_t)bh * NC * HEADDIM * D_STATE;
    for (int k = tid; k < HEADDIM * D_STATE / 4; k += 256) {
        float4 s = {0.f, 0.f, 0.f, 0.f};
        #pragma unroll
        for (int c = 0; c < NC; ++c) {
            float4* ptr = (float4*)(base + (size_t)c * HEADDIM * D_STATE) + k;
            float4 f = *ptr;
            *ptr = s;
            s.x = fmaf(s.x, P[c], f.x);
            s.y = fmaf(s.y, P[c], f.y);
            s.z = fmaf(s.z, P[c], f.z);
            s.w = fmaf(s.w, P[c], f.w);
        }
    }
}

// ---------------- K4c: fix-up y += cumdA_t * (C_t . s_init), LDS y staging ----------------
__global__ __launch_bounds__(256, 4) void k4c_fix(
    const float* __restrict__ xbcc, const float* __restrict__ sinit,
    const float* __restrict__ dcum, float* __restrict__ ybuf)
{
    const int pt = blockIdx.x & 3;
    const int c  = (blockIdx.x >> 2) & 7;
    const int h  = (blockIdx.x >> 5) & 7;
    const int b  = blockIdx.x >> 8;
    if (c == 0) return;
    const int tid = threadIdx.x;
    const int ng = tid & 7;
    const int p  = pt * 32 + (tid >> 3);
    __shared__ float sY[32][36];        // 32 t-rows x 32 p (padded)

    const float* sp = sinit + ((((size_t)(b * NHEADS + h) * NC + c) * HEADDIM + p) * D_STATE + ng * 16);
    const float4 s0 = *(const float4*)sp;
    const float4 s1 = *(const float4*)(sp + 4);
    const float4 s2 = *(const float4*)(sp + 8);
    const float4 s3 = *(const float4*)(sp + 12);

    const size_t mbase = (size_t)b * LSEQ + c * CLEN;
    const float* dcp = dcum + (size_t)(b * NHEADS + h) * LSEQ + c * CLEN;

    float4 Ca[4], Cb[4];
    auto loadC = [&](int t, float4* Cv) {
        const float* row = xbcc + (mbase + t) * CONV_DIM + D_INNER + D_STATE + ng * 16;
        Cv[0] = *(const float4*)(row);
        Cv[1] = *(const float4*)(row + 4);
        Cv[2] = *(const float4*)(row + 8);
        Cv[3] = *(const float4*)(row + 12);
    };
    loadC(0, Ca);

    for (int t = 0; t < CLEN; ++t) {
        float4* Cc = (t & 1) ? Cb : Ca;
        float4* Cn = (t & 1) ? Ca : Cb;
        if (t + 1 < CLEN) loadC(t + 1, Cn);
        float acc;
        acc = s0.x * Cc[0].x;
        acc = fmaf(s0.y, Cc[0].y, acc);
        acc = fmaf(s0.z, Cc[0].z, acc);
        acc = fmaf(s0.w, Cc[0].w, acc);
        acc = fmaf(s1.x, Cc[1].x, acc);
        acc = fmaf(s1.y, Cc[1].y, acc);
        acc = fmaf(s1.z, Cc[1].z, acc);
        acc = fmaf(s1.w, Cc[1].w, acc);
        acc = fmaf(s2.x, Cc[2].x, acc);
        acc = fmaf(s2.y, Cc[2].y, acc);
        acc = fmaf(s2.z, Cc[2].z, acc);
        acc = fmaf(s2.w, Cc[2].w, acc);
        acc = fmaf(s3.x, Cc[3].x, acc);
        acc = fmaf(s3.y, Cc[3].y, acc);
        acc = fmaf(s3.z, Cc[3].z, acc);
        acc = fmaf(s3.w, Cc[3].w, acc);
        acc += __shfl_xor(acc, 1);
        acc += __shfl_xor(acc, 2);
        acc += __shfl_xor(acc, 4);
        if (ng == 0) sY[t & 31][tid >> 3] = dcp[t] * acc;
        if ((t & 31) == 31) {
            __syncthreads();
            int t0f = t - 31;
            int fr = tid >> 3, c4 = (tid & 7) * 4;
            size_t yi = (mbase + t0f + fr) * D_INNER + h * HEADDIM + pt * 32 + c4;
            float4 yv = *(const float4*)(ybuf + yi);
            float4 s = *(const float4*)&sY[fr][c4];
            yv.x += s.x; yv.y += s.y; yv.z += s.z; yv.w += s.w;
            *(float4*)(ybuf + yi) = yv;
            __syncthreads();
        }
    }
}

// ---------------- K5: y *= silu(z); RMSNorm * norm_w ----------------
__global__ __launch_bounds__(256) void k5_norm(
    float* __restrict__ ybuf, const float* __restrict__ zbuf, const float* __restrict__ nw)
{
    const int m = blockIdx.x;
    const int tid = threadIdx.x;
    const size_t off = (size_t)m * D_INNER + tid * 4;
    float4 yv = *(const float4*)(ybuf + off);
    float4 zv = *(const float4*)(zbuf + off);
    float4 g;
    g.x = yv.x * (zv.x / (1.f + expf(-zv.x)));
    g.y = yv.y * (zv.y / (1.f + expf(-zv.y)));
    g.z = yv.z * (zv.z / (1.f + expf(-zv.z)));
    g.w = yv.w * (zv.w / (1.f + expf(-zv.w)));
    float ss = g.x*g.x + g.y*g.y + g.z*g.z + g.w*g.w;
    #pragma unroll
    for (int mask = 1; mask <= 32; mask <<= 1) ss += __shfl_xor(ss, mask);
    __shared__ float red[4];
    if ((tid & 63) == 0) red[tid >> 6] = ss;
    __syncthreads();
    float tot = red[0] + red[1] + red[2] + red[3];
    float scale = rsqrtf(tot * (1.f / 1024.f) + 1e-5f);
    float4 w4 = *(const float4*)(nw + tid * 4);
    g.x *= scale * w4.x;
    g.y *= scale * w4.y;
    g.z *= scale * w4.z;
    g.w *= scale * w4.w;
    *(float4*)(ybuf + off) = g;
}

// ---------------- K6: out_proj GEMM + residual (transposed store) ----------------
__global__ __launch_bounds__(256) void k6_outproj(
    const float* __restrict__ y, const float* __restrict__ W,
    const float* __restrict__ x, float* __restrict__ out)
{
    __shared__ float As[32][68];
    __shared__ float Bs[32][68];
    const int tx = threadIdx.x, ty = threadIdx.y;
    const int tid = ty * 16 + tx;
    const int n0 = blockIdx.x * 64;
    const int m0 = blockIdx.y * 64;
    const int b  = m0 >> 12;
    const int l0 = m0 & 4095;

    float c[4][4] = {};
    const int lk = tid & 31, lr = tid >> 5;

    for (int kb = 0; kb < D_INNER; kb += 32) {
        #pragma unroll
        for (int mm = 0; mm < 8; ++mm) {
            int m = lr * 8 + mm;
            As[lk][m] = y[(size_t)(m0 + m) * D_INNER + kb + lk];
        }
        #pragma unroll
        for (int nn = 0; nn < 8; ++nn) {
            int n = lr * 8 + nn;
            Bs[lk][n] = W[(size_t)(n0 + n) * D_INNER + kb + lk];
        }
        __syncthreads();
        #pragma unroll
        for (int kk = 0; kk < 32; ++kk) {
            float4 a4 = *(const float4*)&As[kk][tx * 4];
            float4 b4 = *(const float4*)&Bs[kk][ty * 4];
            float av_[4] = {a4.x, a4.y, a4.z, a4.w};
            float bv_[4] = {b4.x, b4.y, b4.z, b4.w};
            #pragma unroll
            for (int i = 0; i < 4; ++i)
                #pragma unroll
                for (int j = 0; j < 4; ++j)
                    c[i][j] = fmaf(bv_[i], av_[j], c[i][j]);
        }
        __syncthreads();
    }
    #pragma unroll
    for (int i = 0; i < 4; ++i) {
        int d = n0 + ty * 4 + i;
        size_t o = ((size_t)(b * DIMC + d) << 12) + l0 + tx * 4;
        float4 xr = *(const float4*)(x + o);
        float4 r;
        r.x = c[i][0] + xr.x;
        r.y = c[i][1] + xr.y;
        r.z = c[i][2] + xr.z;
        r.w = c[i][3] + xr.w;
        *(float4*)(out + o) = r;
    }
}

extern "C" void kernel_launch(void* const* d_in, const int* in_sizes, int n_in,
                              void* d_out, int out_size, void* d_ws, size_t ws_size,
                              hipStream_t stream) {
    const float* x          = (const float*)d_in[0];
    const float* in_proj_w  = (const float*)d_in[1];
    const float* conv_w     = (const float*)d_in[2];
    const float* conv_b     = (const float*)d_in[3];
    const float* dt_bias    = (const float*)d_in[4];
    const float* A_log      = (const float*)d_in[5];
    const float* D_param    = (const float*)d_in[6];
    const float* norm_w     = (const float*)d_in[7];
    const float* out_proj_w = (const float*)d_in[8];
    float* out = (float*)d_out;

    float* ws   = (float*)d_ws;
    float* zbuf = ws;                                   // BLTOT*1024
    float* xbc  = zbuf + (size_t)BLTOT * D_INNER;       // BLTOT*1280 (pre-conv)
    float* xbcc = xbc  + (size_t)BLTOT * CONV_DIM;      // BLTOT*1280 (post conv+silu)
    float* dtb  = xbcc + (size_t)BLTOT * CONV_DIM;      // BLTOT*8
    float* dtp  = dtb  + (size_t)BLTOT * NHEADS;        // BLTOT*8
    float* dAb  = dtp  + (size_t)BLTOT * NHEADS;        // BLTOT*8
    float* ybuf = xbc;           // pre-conv xbc dead after K3
    float* dcum = dtb;           // dtb dead after K2
    float* statebuf = out;       // 16.8 MB scratch inside d_out; K6 overwrites all

    k1_inproj<<<dim3(37, 256), dim3(16, 16), 0, stream>>>(x, in_proj_w, zbuf, xbc, dtb);
    k2_dt<<<dim3(512), dim3(256), 0, stream>>>(dtb, dt_bias, A_log, dtp, dAb);
    k3_conv<<<dim3(81920), dim3(256), 0, stream>>>(xbc, conv_w, conv_b, xbcc);
    k4a_scan<<<dim3(2048), dim3(256), 0, stream>>>(xbcc, dtp, dAb, D_param, ybuf, statebuf, dcum);
    k4b_prefix<<<dim3(32), dim3(256), 0, stream>>>(statebuf, dcum);
    k4c_fix<<<dim3(1024), dim3(256), 0, stream>>>(xbcc, statebuf, dcum, ybuf);
    k5_norm<<<dim3(BLTOT), dim3(256), 0, stream>>>(ybuf, zbuf, norm_w);
    k6_outproj<<<dim3(8, 256), dim3(16, 16), 0, stream>>>(ybuf, out_proj_w, x, out);
}

// Round 4
// 1721.992 us; speedup vs baseline: 2.6835x; 2.6835x over previous
//
#include <hip/hip_runtime.h>
#include <cstdint>
#include <cstddef>

#define DIMC     512
#define D_INNER  1024
#define HEADDIM  128
#define NHEADS   8
#define D_STATE  128
#define CONV_DIM 1280
#define D_IN_PROJ 2312
#define BSZ      4
#define LSEQ     4096
#define BLTOT    (BSZ*LSEQ)   // 16384
#define NC       8            // chunks
#define CLEN     (LSEQ/NC)    // 512
#define TS       4            // t-steps per LDS staging round

// ---------------- K1: in_proj GEMM ----------------
__global__ __launch_bounds__(256) void k1_inproj(
    const float* __restrict__ x, const float* __restrict__ W,
    float* __restrict__ zbuf, float* __restrict__ xbc, float* __restrict__ dtb)
{
    __shared__ float As[32][68];
    __shared__ float Bs[32][68];
    const int tx = threadIdx.x, ty = threadIdx.y;
    const int tid = ty * 16 + tx;
    const int n0 = blockIdx.x * 64;
    const int m0 = blockIdx.y * 64;
    const int b  = m0 >> 12;
    const int l0 = m0 & 4095;

    float c[4][4] = {};
    const int am = tid & 63, ak = tid >> 6;
    const int bk = tid & 31, bn = tid >> 5;

    for (int kb = 0; kb < DIMC; kb += 32) {
        #pragma unroll
        for (int kk = 0; kk < 32; kk += 4) {
            As[ak + kk][am] = x[((size_t)(b * DIMC + kb + ak + kk) << 12) + l0 + am];
        }
        #pragma unroll
        for (int nn = 0; nn < 8; ++nn) {
            int n = bn * 8 + nn;
            int e = n0 + n;
            Bs[bk][n] = (e < D_IN_PROJ) ? W[(size_t)e * DIMC + kb + bk] : 0.f;
        }
        __syncthreads();
        #pragma unroll
        for (int kk = 0; kk < 32; ++kk) {
            float4 a4 = *(const float4*)&As[kk][ty * 4];
            float4 b4 = *(const float4*)&Bs[kk][tx * 4];
            float av_[4] = {a4.x, a4.y, a4.z, a4.w};
            float bv_[4] = {b4.x, b4.y, b4.z, b4.w};
            #pragma unroll
            for (int i = 0; i < 4; ++i)
                #pragma unroll
                for (int j = 0; j < 4; ++j)
                    c[i][j] = fmaf(av_[i], bv_[j], c[i][j]);
        }
        __syncthreads();
    }
    #pragma unroll
    for (int i = 0; i < 4; ++i) {
        int m = m0 + ty * 4 + i;
        #pragma unroll
        for (int j = 0; j < 4; ++j) {
            int e = n0 + tx * 4 + j;
            float v = c[i][j];
            if (e < D_INNER)                  zbuf[(size_t)m * D_INNER + e] = v;
            else if (e < D_INNER + CONV_DIM)  xbc[(size_t)m * CONV_DIM + (e - D_INNER)] = v;
            else if (e < D_IN_PROJ)           dtb[(size_t)m * NHEADS + (e - (D_INNER + CONV_DIM))] = v;
        }
    }
}

// ---------------- K2: softplus(dt + bias), dA ----------------
__global__ __launch_bounds__(256) void k2_dt(
    const float* __restrict__ dtb, const float* __restrict__ dt_bias,
    const float* __restrict__ A_log, float* __restrict__ dtp, float* __restrict__ dAb)
{
    int idx = blockIdx.x * 256 + threadIdx.x;
    if (idx >= BLTOT * NHEADS) return;
    int h = idx & 7;
    float v = dtb[idx] + dt_bias[h];
    float sp = (v > 20.f) ? v : log1pf(expf(v));
    dtp[idx] = sp;
    dAb[idx] = expf(sp * (-expf(A_log[h])));
}

// ---------------- K3: causal depthwise conv(4) + SiLU ----------------
__global__ __launch_bounds__(256) void k3_conv(
    const float* __restrict__ xbc, const float* __restrict__ cw,
    const float* __restrict__ cb, float* __restrict__ xbcc)
{
    int idx = blockIdx.x * 256 + threadIdx.x;
    int c = idx % CONV_DIM;
    int m = idx / CONV_DIM;
    int l = m & 4095;
    float acc = cb[c];
    #pragma unroll
    for (int j = 0; j < 4; ++j) {
        if (l - j >= 0)
            acc = fmaf(xbc[(size_t)(m - j) * CONV_DIM + c], cw[c * 4 + (3 - j)], acc);
    }
    xbcc[idx] = acc / (1.f + expf(-acc));
}

// ---------------- K4s: state-only chunk scan ----------------
// block = (b, h, c, pg). Computes chunk-final local states + chunk decay P.
__global__ __launch_bounds__(256, 6) void k4s_state(
    const float* __restrict__ xbcc, const float* __restrict__ dtp,
    const float* __restrict__ dAb,
    float* __restrict__ statebuf, float* __restrict__ Pbuf)
{
    __shared__ float4 sB[2][TS][32];
    __shared__ float4 sX[2][TS][4];
    __shared__ float  sAD[2][TS][2];

    const int tid  = threadIdx.x;
    const int lane = tid & 63;
    const int warp = tid >> 6;
    const int pg = blockIdx.x & 7;
    const int c  = (blockIdx.x >> 3) & 7;
    const int h  = (blockIdx.x >> 6) & 7;
    const int b  = blockIdx.x >> 9;
    const int p  = pg * 16 + warp * 4 + (lane & 3);
    const int nq = (lane >> 2) * 2;
    const size_t mbase = (size_t)b * LSEQ + c * CLEN;

    auto stage = [&](int buf, int r) {
        int t0 = r * TS;
        if (tid < 128) {
            int tl = tid >> 5, q = tid & 31;
            const float* row = xbcc + (mbase + t0 + tl) * CONV_DIM;
            sB[buf][tl][q] = *(const float4*)(row + D_INNER + q * 4);
        } else if (tid < 144) {
            int tl = (tid - 128) >> 2, j = tid & 3;
            const float* row = xbcc + (mbase + t0 + tl) * CONV_DIM;
            sX[buf][tl][j] = *(const float4*)(row + h * HEADDIM + pg * 16 + j * 4);
        } else if (tid < 152) {
            int tl = (tid - 144) >> 1, k = tid & 1;
            size_t idx = (mbase + t0 + tl) * NHEADS + h;
            sAD[buf][tl][k] = k ? dtp[idx] : dAb[idx];
        }
    };

    stage(0, 0);
    __syncthreads();

    float s0=0.f,s1=0.f,s2=0.f,s3=0.f,s4=0.f,s5=0.f,s6=0.f,s7=0.f;
    float cum = 1.f;

    const int NR = CLEN / TS;
    for (int r = 0; r < NR; ++r) {
        const int buf = r & 1;
        if (r + 1 < NR) stage(buf ^ 1, r + 1);
        #pragma unroll
        for (int tl = 0; tl < TS; ++tl) {
            const float4 b0 = sB[buf][tl][nq];
            const float4 b1 = sB[buf][tl][nq + 1];
            const float xt  = ((const float*)&sX[buf][tl][0])[warp * 4 + (lane & 3)];
            const float dAt = sAD[buf][tl][0];
            const float dtt = sAD[buf][tl][1];
            const float dtx = dtt * xt;
            s0 = fmaf(s0, dAt, dtx * b0.x);
            s1 = fmaf(s1, dAt, dtx * b0.y);
            s2 = fmaf(s2, dAt, dtx * b0.z);
            s3 = fmaf(s3, dAt, dtx * b0.w);
            s4 = fmaf(s4, dAt, dtx * b1.x);
            s5 = fmaf(s5, dAt, dtx * b1.y);
            s6 = fmaf(s6, dAt, dtx * b1.z);
            s7 = fmaf(s7, dAt, dtx * b1.w);
            cum *= dAt;
        }
        __syncthreads();
    }

    float* sb = statebuf + ((((size_t)(b * NHEADS + h) * NC + c) * HEADDIM + p) * D_STATE + nq * 4);
    *(float4*)sb       = make_float4(s0, s1, s2, s3);
    *(float4*)(sb + 4) = make_float4(s4, s5, s6, s7);
    if (pg == 0 && tid == 0) Pbuf[(b * NHEADS + h) * NC + c] = cum;
}

// ---------------- K4b: cross-chunk state prefix (in place) ----------------
// statebuf[bh][c][p][n]: final local chunk states -> becomes s_init[c]
__global__ __launch_bounds__(256) void k4b_prefix(
    float* __restrict__ statebuf, const float* __restrict__ Pbuf)
{
    const int bh = blockIdx.x;
    const int tid = threadIdx.x;
    float P[NC];
    #pragma unroll
    for (int c = 0; c < NC; ++c) P[c] = Pbuf[bh * NC + c];
    float* base = statebuf + (size_t)bh * NC * HEADDIM * D_STATE;
    for (int k = tid; k < HEADDIM * D_STATE / 4; k += 256) {
        float4 s = {0.f, 0.f, 0.f, 0.f};
        #pragma unroll
        for (int c = 0; c < NC; ++c) {
            float4* ptr = (float4*)(base + (size_t)c * HEADDIM * D_STATE) + k;
            float4 f = *ptr;
            *ptr = s;
            s.x = fmaf(s.x, P[c], f.x);
            s.y = fmaf(s.y, P[c], f.y);
            s.z = fmaf(s.z, P[c], f.z);
            s.w = fmaf(s.w, P[c], f.w);
        }
    }
}

// ---------------- K4a_final: exact chunk scan seeded with s_init, writes final y ----------------
__global__ __launch_bounds__(256, 6) void k4a_final(
    const float* __restrict__ xbcc, const float* __restrict__ dtp,
    const float* __restrict__ dAb, const float* __restrict__ Dp,
    const float* __restrict__ sinit, float* __restrict__ ybuf)
{
    __shared__ float4 sBC[2][TS][64];
    __shared__ float4 sX[2][TS][4];
    __shared__ float  sAD[2][TS][2];
    __shared__ float  sY[32][20];

    const int tid  = threadIdx.x;
    const int lane = tid & 63;
    const int warp = tid >> 6;
    const int pg = blockIdx.x & 7;
    const int c  = (blockIdx.x >> 3) & 7;
    const int h  = (blockIdx.x >> 6) & 7;
    const int b  = blockIdx.x >> 9;
    const int p  = pg * 16 + warp * 4 + (lane & 3);
    const int nq = (lane >> 2) * 2;
    const float Dh = Dp[h];
    const size_t mbase = (size_t)b * LSEQ + c * CLEN;

    const int ld_t = tid >> 6;
    const int ld_q = tid & 63;

    auto stage = [&](int buf, int r) {
        int t0 = r * TS;
        {
            const float* row = xbcc + (mbase + t0 + ld_t) * CONV_DIM;
            sBC[buf][ld_t][ld_q] = *(const float4*)(row + D_INNER + ld_q * 4);
        }
        if (tid < 16) {
            int tl = tid >> 2, j = tid & 3;
            const float* row = xbcc + (mbase + t0 + tl) * CONV_DIM;
            sX[buf][tl][j] = *(const float4*)(row + h * HEADDIM + pg * 16 + j * 4);
        } else if (tid < 24) {
            int tl = (tid - 16) >> 1, k = tid & 1;
            size_t idx = (mbase + t0 + tl) * NHEADS + h;
            sAD[buf][tl][k] = k ? dtp[idx] : dAb[idx];
        }
    };

    // seed state from s_init (computed by k4s + k4b)
    const float* sbi = sinit + ((((size_t)(b * NHEADS + h) * NC + c) * HEADDIM + p) * D_STATE + nq * 4);
    const float4 i0 = *(const float4*)sbi;
    const float4 i1 = *(const float4*)(sbi + 4);
    float s0=i0.x, s1=i0.y, s2=i0.z, s3=i0.w;
    float s4=i1.x, s5=i1.y, s6=i1.z, s7=i1.w;

    stage(0, 0);
    __syncthreads();

    const int NR = CLEN / TS;
    for (int r = 0; r < NR; ++r) {
        const int buf = r & 1;
        if (r + 1 < NR) stage(buf ^ 1, r + 1);
        #pragma unroll
        for (int tl = 0; tl < TS; ++tl) {
            const float4 b0 = sBC[buf][tl][nq];
            const float4 b1 = sBC[buf][tl][nq + 1];
            const float4 c0 = sBC[buf][tl][32 + nq];
            const float4 c1 = sBC[buf][tl][32 + nq + 1];
            const float xt  = ((const float*)&sX[buf][tl][0])[warp * 4 + (lane & 3)];
            const float dAt = sAD[buf][tl][0];
            const float dtt = sAD[buf][tl][1];

            const float dtx = dtt * xt;
            float y0, y1;
            s0 = fmaf(s0, dAt, dtx * b0.x); y0 = s0 * c0.x;
            s1 = fmaf(s1, dAt, dtx * b0.y); y1 = s1 * c0.y;
            s2 = fmaf(s2, dAt, dtx * b0.z); y0 = fmaf(s2, c0.z, y0);
            s3 = fmaf(s3, dAt, dtx * b0.w); y1 = fmaf(s3, c0.w, y1);
            s4 = fmaf(s4, dAt, dtx * b1.x); y0 = fmaf(s4, c1.x, y0);
            s5 = fmaf(s5, dAt, dtx * b1.y); y1 = fmaf(s5, c1.y, y1);
            s6 = fmaf(s6, dAt, dtx * b1.z); y0 = fmaf(s6, c1.z, y0);
            s7 = fmaf(s7, dAt, dtx * b1.w); y1 = fmaf(s7, c1.w, y1);
            float y = y0 + y1;
            y += __shfl_xor(y, 4);
            y += __shfl_xor(y, 8);
            y += __shfl_xor(y, 16);
            y += __shfl_xor(y, 32);
            if (lane < 4) sY[(r * TS + tl) & 31][warp * 4 + lane] = fmaf(Dh, xt, y);
        }
        __syncthreads();
        if ((r & 7) == 7) {
            int t0f = (r - 7) * TS;
            if (tid < 128) {
                int fr = tid >> 2, c4 = (tid & 3) * 4;
                float4 v = *(const float4*)&sY[fr][c4];
                *(float4*)(ybuf + (mbase + t0f + fr) * D_INNER + h * HEADDIM + pg * 16 + c4) = v;
            }
            __syncthreads();
        }
    }
}

// ---------------- K5: y *= silu(z); RMSNorm * norm_w ----------------
__global__ __launch_bounds__(256) void k5_norm(
    float* __restrict__ ybuf, const float* __restrict__ zbuf, const float* __restrict__ nw)
{
    const int m = blockIdx.x;
    const int tid = threadIdx.x;
    const size_t off = (size_t)m * D_INNER + tid * 4;
    float4 yv = *(const float4*)(ybuf + off);
    float4 zv = *(const float4*)(zbuf + off);
    float4 g;
    g.x = yv.x * (zv.x / (1.f + expf(-zv.x)));
    g.y = yv.y * (zv.y / (1.f + expf(-zv.y)));
    g.z = yv.z * (zv.z / (1.f + expf(-zv.z)));
    g.w = yv.w * (zv.w / (1.f + expf(-zv.w)));
    float ss = g.x*g.x + g.y*g.y + g.z*g.z + g.w*g.w;
    #pragma unroll
    for (int mask = 1; mask <= 32; mask <<= 1) ss += __shfl_xor(ss, mask);
    __shared__ float red[4];
    if ((tid & 63) == 0) red[tid >> 6] = ss;
    __syncthreads();
    float tot = red[0] + red[1] + red[2] + red[3];
    float scale = rsqrtf(tot * (1.f / 1024.f) + 1e-5f);
    float4 w4 = *(const float4*)(nw + tid * 4);
    g.x *= scale * w4.x;
    g.y *= scale * w4.y;
    g.z *= scale * w4.z;
    g.w *= scale * w4.w;
    *(float4*)(ybuf + off) = g;
}

// ---------------- K6: out_proj GEMM + residual (transposed store) ----------------
__global__ __launch_bounds__(256) void k6_outproj(
    const float* __restrict__ y, const float* __restrict__ W,
    const float* __restrict__ x, float* __restrict__ out)
{
    __shared__ float As[32][68];
    __shared__ float Bs[32][68];
    const int tx = threadIdx.x, ty = threadIdx.y;
    const int tid = ty * 16 + tx;
    const int n0 = blockIdx.x * 64;
    const int m0 = blockIdx.y * 64;
    const int b  = m0 >> 12;
    const int l0 = m0 & 4095;

    float c[4][4] = {};
    const int lk = tid & 31, lr = tid >> 5;

    for (int kb = 0; kb < D_INNER; kb += 32) {
        #pragma unroll
        for (int mm = 0; mm < 8; ++mm) {
            int m = lr * 8 + mm;
            As[lk][m] = y[(size_t)(m0 + m) * D_INNER + kb + lk];
        }
        #pragma unroll
        for (int nn = 0; nn < 8; ++nn) {
            int n = lr * 8 + nn;
            Bs[lk][n] = W[(size_t)(n0 + n) * D_INNER + kb + lk];
        }
        __syncthreads();
        #pragma unroll
        for (int kk = 0; kk < 32; ++kk) {
            float4 a4 = *(const float4*)&As[kk][tx * 4];
            float4 b4 = *(const float4*)&Bs[kk][ty * 4];
            float av_[4] = {a4.x, a4.y, a4.z, a4.w};
            float bv_[4] = {b4.x, b4.y, b4.z, b4.w};
            #pragma unroll
            for (int i = 0; i < 4; ++i)
                #pragma unroll
                for (int j = 0; j < 4; ++j)
                    c[i][j] = fmaf(bv_[i], av_[j], c[i][j]);
        }
        __syncthreads();
    }
    #pragma unroll
    for (int i = 0; i < 4; ++i) {
        int d = n0 + ty * 4 + i;
        size_t o = ((size_t)(b * DIMC + d) << 12) + l0 + tx * 4;
        float4 xr = *(const float4*)(x + o);
        float4 r;
        r.x = c[i][0] + xr.x;
        r.y = c[i][1] + xr.y;
        r.z = c[i][2] + xr.z;
        r.w = c[i][3] + xr.w;
        *(float4*)(out + o) = r;
    }
}

extern "C" void kernel_launch(void* const* d_in, const int* in_sizes, int n_in,
                              void* d_out, int out_size, void* d_ws, size_t ws_size,
                              hipStream_t stream) {
    const float* x          = (const float*)d_in[0];
    const float* in_proj_w  = (const float*)d_in[1];
    const float* conv_w     = (const float*)d_in[2];
    const float* conv_b     = (const float*)d_in[3];
    const float* dt_bias    = (const float*)d_in[4];
    const float* A_log      = (const float*)d_in[5];
    const float* D_param    = (const float*)d_in[6];
    const float* norm_w     = (const float*)d_in[7];
    const float* out_proj_w = (const float*)d_in[8];
    float* out = (float*)d_out;

    float* ws   = (float*)d_ws;
    float* zbuf = ws;                                   // BLTOT*1024
    float* xbc  = zbuf + (size_t)BLTOT * D_INNER;       // BLTOT*1280 (pre-conv)
    float* xbcc = xbc  + (size_t)BLTOT * CONV_DIM;      // BLTOT*1280 (post conv+silu)
    float* dtb  = xbcc + (size_t)BLTOT * CONV_DIM;      // BLTOT*8
    float* dtp  = dtb  + (size_t)BLTOT * NHEADS;        // BLTOT*8
    float* dAb  = dtp  + (size_t)BLTOT * NHEADS;        // BLTOT*8
    float* Pbuf = dAb  + (size_t)BLTOT * NHEADS;        // 256 floats
    float* ybuf = xbc;           // pre-conv xbc dead after K3
    float* statebuf = out;       // 16.8 MB scratch inside d_out; K6 overwrites all

    k1_inproj<<<dim3(37, 256), dim3(16, 16), 0, stream>>>(x, in_proj_w, zbuf, xbc, dtb);
    k2_dt<<<dim3(512), dim3(256), 0, stream>>>(dtb, dt_bias, A_log, dtp, dAb);
    k3_conv<<<dim3(81920), dim3(256), 0, stream>>>(xbc, conv_w, conv_b, xbcc);
    k4s_state<<<dim3(2048), dim3(256), 0, stream>>>(xbcc, dtp, dAb, statebuf, Pbuf);
    k4b_prefix<<<dim3(32), dim3(256), 0, stream>>>(statebuf, Pbuf);
    k4a_final<<<dim3(2048), dim3(256), 0, stream>>>(xbcc, dtp, dAb, D_param, statebuf, ybuf);
    k5_norm<<<dim3(BLTOT), dim3(256), 0, stream>>>(ybuf, zbuf, norm_w);
    k6_outproj<<<dim3(8, 256), dim3(16, 16), 0, stream>>>(ybuf, out_proj_w, x, out);
}

// Round 5
// 998.150 us; speedup vs baseline: 4.6295x; 1.7252x over previous
//
#include <hip/hip_runtime.h>
#include <cstdint>
#include <cstddef>

#define DIMC     512
#define D_INNER  1024
#define HEADDIM  128
#define NHEADS   8
#define D_STATE  128
#define CONV_DIM 1280
#define D_IN_PROJ 2312
#define NPAD     2432         // D_IN_PROJ padded to 128
#define BSZ      4
#define LSEQ     4096
#define BLTOT    (BSZ*LSEQ)   // 16384
#define NC       8            // chunks
#define CLEN     (LSEQ/NC)    // 512
#define TS       4            // t-steps per LDS staging round

typedef short bf16x8 __attribute__((ext_vector_type(8)));
typedef float f32x4  __attribute__((ext_vector_type(4)));

__device__ inline ushort f2bf(float f) {
    uint32_t u = __float_as_uint(f);
    uint32_t r = (u + 0x7FFFu + ((u >> 16) & 1u)) >> 16;
    return (ushort)r;
}

// ---------------- K0a: transpose + convert x [b,d,l] fp32 -> xT [b,l,d] bf16 ----------------
__global__ __launch_bounds__(256) void k0a_xT(const float* __restrict__ x, ushort* __restrict__ xT)
{
    __shared__ float t[32][33];
    const int bx = blockIdx.x;
    const int lt = bx & 127, dt = (bx >> 7) & 15, b = bx >> 11;
    const int r = threadIdx.x >> 5, c = threadIdx.x & 31;
    #pragma unroll
    for (int i = 0; i < 4; ++i) {
        int d = dt * 32 + r + i * 8;
        t[r + i * 8][c] = x[((size_t)(b * DIMC + d) << 12) + lt * 32 + c];
    }
    __syncthreads();
    #pragma unroll
    for (int i = 0; i < 4; ++i) {
        int l = lt * 32 + r + i * 8;
        xT[((size_t)(b * LSEQ + l)) * DIMC + dt * 32 + c] = f2bf(t[c][r + i * 8]);
    }
}

// ---------------- K0b: convert + pad in_proj_w -> bf16 [2432][512] ----------------
__global__ __launch_bounds__(256) void k0b_wb(const float* __restrict__ W, ushort* __restrict__ Wb)
{
    int i4 = (blockIdx.x * 256 + threadIdx.x) * 4;   // NPAD*512 exact
    int e = i4 >> 9;
    ushort4 o;
    if (e < D_IN_PROJ) {
        float4 v = *(const float4*)(W + (size_t)e * DIMC + (i4 & 511));
        o.x = f2bf(v.x); o.y = f2bf(v.y); o.z = f2bf(v.z); o.w = f2bf(v.w);
    } else { o.x = o.y = o.z = o.w = 0; }
    *(ushort4*)(Wb + i4) = o;
}

// ---------------- K0c: convert out_proj_w -> bf16 [512][1024] ----------------
__global__ __launch_bounds__(256) void k0c_wout(const float* __restrict__ W, ushort* __restrict__ Wb)
{
    int i4 = (blockIdx.x * 256 + threadIdx.x) * 4;   // 512*1024 exact
    float4 v = *(const float4*)(W + i4);
    ushort4 o;
    o.x = f2bf(v.x); o.y = f2bf(v.y); o.z = f2bf(v.z); o.w = f2bf(v.w);
    *(ushort4*)(Wb + i4) = o;
}

// ---------------- K1: in_proj GEMM, bf16 MFMA ----------------
// C[m,e] = sum_k xT[m,k]*Wb[e,k]. 128x128x32 tile, 4 waves of 64x64.
__global__ __launch_bounds__(256) void k1_mfma(
    const ushort* __restrict__ A, const ushort* __restrict__ B,
    float* __restrict__ zbuf, float* __restrict__ xbc, float* __restrict__ dtb)
{
    __shared__ ushort sA[128 * 32];
    __shared__ ushort sB[128 * 32];
    const int tid = threadIdx.x;
    const int lane = tid & 63;
    const int wv = tid >> 6;
    const int wm = (wv & 1) * 64, wn = (wv >> 1) * 64;
    const int m0 = blockIdx.x * 128;
    const int n0 = blockIdx.y * 128;

    f32x4 acc[4][4];
    #pragma unroll
    for (int i = 0; i < 4; ++i)
        #pragma unroll
        for (int j = 0; j < 4; ++j) acc[i][j] = (f32x4){0.f, 0.f, 0.f, 0.f};

    // staging slots: s in {tid, tid+256}; row=s>>2, chunk=s&3, k8 = chunk ^ ((row>>1)&3)
    const int s0_ = tid, s1_ = tid + 256;
    const int r0 = s0_ >> 2, c0 = s0_ & 3, k80 = c0 ^ ((r0 >> 1) & 3);
    const int r1 = s1_ >> 2, c1 = s1_ & 3, k81 = c1 ^ ((r1 >> 1) & 3);

    const int quad = lane >> 4, col = lane & 15;

    for (int kb = 0; kb < DIMC; kb += 32) {
        int4 a0 = *(const int4*)(A + (size_t)(m0 + r0) * DIMC + kb + k80 * 8);
        int4 a1 = *(const int4*)(A + (size_t)(m0 + r1) * DIMC + kb + k81 * 8);
        int4 b0 = *(const int4*)(B + (size_t)(n0 + r0) * DIMC + kb + k80 * 8);
        int4 b1 = *(const int4*)(B + (size_t)(n0 + r1) * DIMC + kb + k81 * 8);
        __syncthreads();
        *(int4*)&sA[s0_ * 8] = a0;
        *(int4*)&sA[s1_ * 8] = a1;
        *(int4*)&sB[s0_ * 8] = b0;
        *(int4*)&sB[s1_ * 8] = b1;
        __syncthreads();
        bf16x8 af[4], bf[4];
        #pragma unroll
        for (int mi = 0; mi < 4; ++mi) {
            int m = wm + mi * 16 + col;
            int ch = quad ^ ((m >> 1) & 3);
            af[mi] = *(const bf16x8*)&sA[m * 32 + ch * 8];
        }
        #pragma unroll
        for (int ni = 0; ni < 4; ++ni) {
            int n = wn + ni * 16 + col;
            int ch = quad ^ ((n >> 1) & 3);
            bf[ni] = *(const bf16x8*)&sB[n * 32 + ch * 8];
        }
        #pragma unroll
        for (int mi = 0; mi < 4; ++mi)
            #pragma unroll
            for (int ni = 0; ni < 4; ++ni)
                acc[mi][ni] = __builtin_amdgcn_mfma_f32_16x16x32_bf16(af[mi], bf[ni], acc[mi][ni], 0, 0, 0);
    }

    #pragma unroll
    for (int mi = 0; mi < 4; ++mi) {
        #pragma unroll
        for (int ni = 0; ni < 4; ++ni) {
            int e = n0 + wn + ni * 16 + col;
            #pragma unroll
            for (int reg = 0; reg < 4; ++reg) {
                int m = m0 + wm + mi * 16 + quad * 4 + reg;
                float v = acc[mi][ni][reg];
                if (e < D_INNER)                  zbuf[(size_t)m * D_INNER + e] = v;
                else if (e < D_INNER + CONV_DIM)  xbc[(size_t)m * CONV_DIM + (e - D_INNER)] = v;
                else if (e < D_IN_PROJ)           dtb[(size_t)m * NHEADS + (e - (D_INNER + CONV_DIM))] = v;
            }
        }
    }
}

// ---------------- K6: out_proj GEMM bf16 MFMA + residual, transposed store ----------------
// A = WoutB [512][1024] (d-major), B = ybB [16384][1024]; D[d][m], store out[b,d,l]+x
__global__ __launch_bounds__(256) void k6_mfma(
    const ushort* __restrict__ A, const ushort* __restrict__ B,
    const float* __restrict__ x, float* __restrict__ out)
{
    __shared__ ushort sA[128 * 32];
    __shared__ ushort sB[128 * 32];
    const int tid = threadIdx.x;
    const int lane = tid & 63;
    const int wv = tid >> 6;
    const int wm = (wv & 1) * 64, wn = (wv >> 1) * 64;
    const int m0 = blockIdx.x * 128;   // d
    const int n0 = blockIdx.y * 128;   // m=(b,l)

    f32x4 acc[4][4];
    #pragma unroll
    for (int i = 0; i < 4; ++i)
        #pragma unroll
        for (int j = 0; j < 4; ++j) acc[i][j] = (f32x4){0.f, 0.f, 0.f, 0.f};

    const int s0_ = tid, s1_ = tid + 256;
    const int r0 = s0_ >> 2, c0 = s0_ & 3, k80 = c0 ^ ((r0 >> 1) & 3);
    const int r1 = s1_ >> 2, c1 = s1_ & 3, k81 = c1 ^ ((r1 >> 1) & 3);
    const int quad = lane >> 4, col = lane & 15;

    for (int kb = 0; kb < D_INNER; kb += 32) {
        int4 a0 = *(const int4*)(A + (size_t)(m0 + r0) * D_INNER + kb + k80 * 8);
        int4 a1 = *(const int4*)(A + (size_t)(m0 + r1) * D_INNER + kb + k81 * 8);
        int4 b0 = *(const int4*)(B + (size_t)(n0 + r0) * D_INNER + kb + k80 * 8);
        int4 b1 = *(const int4*)(B + (size_t)(n0 + r1) * D_INNER + kb + k81 * 8);
        __syncthreads();
        *(int4*)&sA[s0_ * 8] = a0;
        *(int4*)&sA[s1_ * 8] = a1;
        *(int4*)&sB[s0_ * 8] = b0;
        *(int4*)&sB[s1_ * 8] = b1;
        __syncthreads();
        bf16x8 af[4], bf[4];
        #pragma unroll
        for (int mi = 0; mi < 4; ++mi) {
            int m = wm + mi * 16 + col;
            int ch = quad ^ ((m >> 1) & 3);
            af[mi] = *(const bf16x8*)&sA[m * 32 + ch * 8];
        }
        #pragma unroll
        for (int ni = 0; ni < 4; ++ni) {
            int n = wn + ni * 16 + col;
            int ch = quad ^ ((n >> 1) & 3);
            bf[ni] = *(const bf16x8*)&sB[n * 32 + ch * 8];
        }
        #pragma unroll
        for (int mi = 0; mi < 4; ++mi)
            #pragma unroll
            for (int ni = 0; ni < 4; ++ni)
                acc[mi][ni] = __builtin_amdgcn_mfma_f32_16x16x32_bf16(af[mi], bf[ni], acc[mi][ni], 0, 0, 0);
    }

    #pragma unroll
    for (int mi = 0; mi < 4; ++mi) {
        #pragma unroll
        for (int ni = 0; ni < 4; ++ni) {
            int mm = n0 + wn + ni * 16 + col;
            int b = mm >> 12, l = mm & 4095;
            #pragma unroll
            for (int reg = 0; reg < 4; ++reg) {
                int d = m0 + wm + mi * 16 + quad * 4 + reg;
                size_t o = ((size_t)(b * DIMC + d) << 12) + l;
                out[o] = acc[mi][ni][reg] + x[o];
            }
        }
    }
}

// ---------------- K2: softplus(dt + bias), dA ----------------
__global__ __launch_bounds__(256) void k2_dt(
    const float* __restrict__ dtb, const float* __restrict__ dt_bias,
    const float* __restrict__ A_log, float* __restrict__ dtp, float* __restrict__ dAb)
{
    int idx = blockIdx.x * 256 + threadIdx.x;
    if (idx >= BLTOT * NHEADS) return;
    int h = idx & 7;
    float v = dtb[idx] + dt_bias[h];
    float sp = (v > 20.f) ? v : log1pf(expf(v));
    dtp[idx] = sp;
    dAb[idx] = expf(sp * (-expf(A_log[h])));
}

// ---------------- K3: causal depthwise conv(4) + SiLU ----------------
__global__ __launch_bounds__(256) void k3_conv(
    const float* __restrict__ xbc, const float* __restrict__ cw,
    const float* __restrict__ cb, float* __restrict__ xbcc)
{
    int idx = blockIdx.x * 256 + threadIdx.x;
    int c = idx % CONV_DIM;
    int m = idx / CONV_DIM;
    int l = m & 4095;
    float acc = cb[c];
    #pragma unroll
    for (int j = 0; j < 4; ++j) {
        if (l - j >= 0)
            acc = fmaf(xbc[(size_t)(m - j) * CONV_DIM + c], cw[c * 4 + (3 - j)], acc);
    }
    xbcc[idx] = acc / (1.f + expf(-acc));
}

// ---------------- K4s: state-only chunk scan ----------------
__global__ __launch_bounds__(256, 6) void k4s_state(
    const float* __restrict__ xbcc, const float* __restrict__ dtp,
    const float* __restrict__ dAb,
    float* __restrict__ statebuf, float* __restrict__ Pbuf)
{
    __shared__ float4 sB[2][TS][32];
    __shared__ float4 sX[2][TS][4];
    __shared__ float  sAD[2][TS][2];

    const int tid  = threadIdx.x;
    const int lane = tid & 63;
    const int warp = tid >> 6;
    const int pg = blockIdx.x & 7;
    const int c  = (blockIdx.x >> 3) & 7;
    const int h  = (blockIdx.x >> 6) & 7;
    const int b  = blockIdx.x >> 9;
    const int p  = pg * 16 + warp * 4 + (lane & 3);
    const int nq = (lane >> 2) * 2;
    const size_t mbase = (size_t)b * LSEQ + c * CLEN;

    auto stage = [&](int buf, int r) {
        int t0 = r * TS;
        if (tid < 128) {
            int tl = tid >> 5, q = tid & 31;
            const float* row = xbcc + (mbase + t0 + tl) * CONV_DIM;
            sB[buf][tl][q] = *(const float4*)(row + D_INNER + q * 4);
        } else if (tid < 144) {
            int tl = (tid - 128) >> 2, j = tid & 3;
            const float* row = xbcc + (mbase + t0 + tl) * CONV_DIM;
            sX[buf][tl][j] = *(const float4*)(row + h * HEADDIM + pg * 16 + j * 4);
        } else if (tid < 152) {
            int tl = (tid - 144) >> 1, k = tid & 1;
            size_t idx = (mbase + t0 + tl) * NHEADS + h;
            sAD[buf][tl][k] = k ? dtp[idx] : dAb[idx];
        }
    };

    stage(0, 0);
    __syncthreads();

    float s0=0.f,s1=0.f,s2=0.f,s3=0.f,s4=0.f,s5=0.f,s6=0.f,s7=0.f;
    float cum = 1.f;

    const int NR = CLEN / TS;
    for (int r = 0; r < NR; ++r) {
        const int buf = r & 1;
        if (r + 1 < NR) stage(buf ^ 1, r + 1);
        #pragma unroll
        for (int tl = 0; tl < TS; ++tl) {
            const float4 b0 = sB[buf][tl][nq];
            const float4 b1 = sB[buf][tl][nq + 1];
            const float xt  = ((const float*)&sX[buf][tl][0])[warp * 4 + (lane & 3)];
            const float dAt = sAD[buf][tl][0];
            const float dtt = sAD[buf][tl][1];
            const float dtx = dtt * xt;
            s0 = fmaf(s0, dAt, dtx * b0.x);
            s1 = fmaf(s1, dAt, dtx * b0.y);
            s2 = fmaf(s2, dAt, dtx * b0.z);
            s3 = fmaf(s3, dAt, dtx * b0.w);
            s4 = fmaf(s4, dAt, dtx * b1.x);
            s5 = fmaf(s5, dAt, dtx * b1.y);
            s6 = fmaf(s6, dAt, dtx * b1.z);
            s7 = fmaf(s7, dAt, dtx * b1.w);
            cum *= dAt;
        }
        __syncthreads();
    }

    float* sb = statebuf + ((((size_t)(b * NHEADS + h) * NC + c) * HEADDIM + p) * D_STATE + nq * 4);
    *(float4*)sb       = make_float4(s0, s1, s2, s3);
    *(float4*)(sb + 4) = make_float4(s4, s5, s6, s7);
    if (pg == 0 && tid == 0) Pbuf[(b * NHEADS + h) * NC + c] = cum;
}

// ---------------- K4b: cross-chunk state prefix (in place) ----------------
__global__ __launch_bounds__(256) void k4b_prefix(
    float* __restrict__ statebuf, const float* __restrict__ Pbuf)
{
    const int bh = blockIdx.x;
    const int tid = threadIdx.x;
    float P[NC];
    #pragma unroll
    for (int c = 0; c < NC; ++c) P[c] = Pbuf[bh * NC + c];
    float* base = statebuf + (size_t)bh * NC * HEADDIM * D_STATE;
    for (int k = tid; k < HEADDIM * D_STATE / 4; k += 256) {
        float4 s = {0.f, 0.f, 0.f, 0.f};
        #pragma unroll
        for (int c = 0; c < NC; ++c) {
            float4* ptr = (float4*)(base + (size_t)c * HEADDIM * D_STATE) + k;
            float4 f = *ptr;
            *ptr = s;
            s.x = fmaf(s.x, P[c], f.x);
            s.y = fmaf(s.y, P[c], f.y);
            s.z = fmaf(s.z, P[c], f.z);
            s.w = fmaf(s.w, P[c], f.w);
        }
    }
}

// ---------------- K4a_final: exact chunk scan seeded with s_init, writes final y ----------------
__global__ __launch_bounds__(256, 6) void k4a_final(
    const float* __restrict__ xbcc, const float* __restrict__ dtp,
    const float* __restrict__ dAb, const float* __restrict__ Dp,
    const float* __restrict__ sinit, float* __restrict__ ybuf)
{
    __shared__ float4 sBC[2][TS][64];
    __shared__ float4 sX[2][TS][4];
    __shared__ float  sAD[2][TS][2];
    __shared__ float  sY[32][20];

    const int tid  = threadIdx.x;
    const int lane = tid & 63;
    const int warp = tid >> 6;
    const int pg = blockIdx.x & 7;
    const int c  = (blockIdx.x >> 3) & 7;
    const int h  = (blockIdx.x >> 6) & 7;
    const int b  = blockIdx.x >> 9;
    const int p  = pg * 16 + warp * 4 + (lane & 3);
    const int nq = (lane >> 2) * 2;
    const float Dh = Dp[h];
    const size_t mbase = (size_t)b * LSEQ + c * CLEN;

    const int ld_t = tid >> 6;
    const int ld_q = tid & 63;

    auto stage = [&](int buf, int r) {
        int t0 = r * TS;
        {
            const float* row = xbcc + (mbase + t0 + ld_t) * CONV_DIM;
            sBC[buf][ld_t][ld_q] = *(const float4*)(row + D_INNER + ld_q * 4);
        }
        if (tid < 16) {
            int tl = tid >> 2, j = tid & 3;
            const float* row = xbcc + (mbase + t0 + tl) * CONV_DIM;
            sX[buf][tl][j] = *(const float4*)(row + h * HEADDIM + pg * 16 + j * 4);
        } else if (tid < 24) {
            int tl = (tid - 16) >> 1, k = tid & 1;
            size_t idx = (mbase + t0 + tl) * NHEADS + h;
            sAD[buf][tl][k] = k ? dtp[idx] : dAb[idx];
        }
    };

    const float* sbi = sinit + ((((size_t)(b * NHEADS + h) * NC + c) * HEADDIM + p) * D_STATE + nq * 4);
    const float4 i0 = *(const float4*)sbi;
    const float4 i1 = *(const float4*)(sbi + 4);
    float s0=i0.x, s1=i0.y, s2=i0.z, s3=i0.w;
    float s4=i1.x, s5=i1.y, s6=i1.z, s7=i1.w;

    stage(0, 0);
    __syncthreads();

    const int NR = CLEN / TS;
    for (int r = 0; r < NR; ++r) {
        const int buf = r & 1;
        if (r + 1 < NR) stage(buf ^ 1, r + 1);
        #pragma unroll
        for (int tl = 0; tl < TS; ++tl) {
            const float4 b0 = sBC[buf][tl][nq];
            const float4 b1 = sBC[buf][tl][nq + 1];
            const float4 c0 = sBC[buf][tl][32 + nq];
            const float4 c1 = sBC[buf][tl][32 + nq + 1];
            const float xt  = ((const float*)&sX[buf][tl][0])[warp * 4 + (lane & 3)];
            const float dAt = sAD[buf][tl][0];
            const float dtt = sAD[buf][tl][1];

            const float dtx = dtt * xt;
            float y0, y1;
            s0 = fmaf(s0, dAt, dtx * b0.x); y0 = s0 * c0.x;
            s1 = fmaf(s1, dAt, dtx * b0.y); y1 = s1 * c0.y;
            s2 = fmaf(s2, dAt, dtx * b0.z); y0 = fmaf(s2, c0.z, y0);
            s3 = fmaf(s3, dAt, dtx * b0.w); y1 = fmaf(s3, c0.w, y1);
            s4 = fmaf(s4, dAt, dtx * b1.x); y0 = fmaf(s4, c1.x, y0);
            s5 = fmaf(s5, dAt, dtx * b1.y); y1 = fmaf(s5, c1.y, y1);
            s6 = fmaf(s6, dAt, dtx * b1.z); y0 = fmaf(s6, c1.z, y0);
            s7 = fmaf(s7, dAt, dtx * b1.w); y1 = fmaf(s7, c1.w, y1);
            float y = y0 + y1;
            y += __shfl_xor(y, 4);
            y += __shfl_xor(y, 8);
            y += __shfl_xor(y, 16);
            y += __shfl_xor(y, 32);
            if (lane < 4) sY[(r * TS + tl) & 31][warp * 4 + lane] = fmaf(Dh, xt, y);
        }
        __syncthreads();
        if ((r & 7) == 7) {
            int t0f = (r - 7) * TS;
            if (tid < 128) {
                int fr = tid >> 2, c4 = (tid & 3) * 4;
                float4 v = *(const float4*)&sY[fr][c4];
                *(float4*)(ybuf + (mbase + t0f + fr) * D_INNER + h * HEADDIM + pg * 16 + c4) = v;
            }
            __syncthreads();
        }
    }
}

// ---------------- K5: y *= silu(z); RMSNorm * norm_w -> bf16 out ----------------
__global__ __launch_bounds__(256) void k5_norm(
    const float* __restrict__ ybuf, const float* __restrict__ zbuf,
    const float* __restrict__ nw, ushort* __restrict__ ybB)
{
    const int m = blockIdx.x;
    const int tid = threadIdx.x;
    const size_t off = (size_t)m * D_INNER + tid * 4;
    float4 yv = *(const float4*)(ybuf + off);
    float4 zv = *(const float4*)(zbuf + off);
    float4 g;
    g.x = yv.x * (zv.x / (1.f + expf(-zv.x)));
    g.y = yv.y * (zv.y / (1.f + expf(-zv.y)));
    g.z = yv.z * (zv.z / (1.f + expf(-zv.z)));
    g.w = yv.w * (zv.w / (1.f + expf(-zv.w)));
    float ss = g.x*g.x + g.y*g.y + g.z*g.z + g.w*g.w;
    #pragma unroll
    for (int mask = 1; mask <= 32; mask <<= 1) ss += __shfl_xor(ss, mask);
    __shared__ float red[4];
    if ((tid & 63) == 0) red[tid >> 6] = ss;
    __syncthreads();
    float tot = red[0] + red[1] + red[2] + red[3];
    float scale = rsqrtf(tot * (1.f / 1024.f) + 1e-5f);
    float4 w4 = *(const float4*)(nw + tid * 4);
    ushort4 ob;
    ob.x = f2bf(g.x * scale * w4.x);
    ob.y = f2bf(g.y * scale * w4.y);
    ob.z = f2bf(g.z * scale * w4.z);
    ob.w = f2bf(g.w * scale * w4.w);
    *(ushort4*)(ybB + off) = ob;
}

extern "C" void kernel_launch(void* const* d_in, const int* in_sizes, int n_in,
                              void* d_out, int out_size, void* d_ws, size_t ws_size,
                              hipStream_t stream) {
    const float* x          = (const float*)d_in[0];
    const float* in_proj_w  = (const float*)d_in[1];
    const float* conv_w     = (const float*)d_in[2];
    const float* conv_b     = (const float*)d_in[3];
    const float* dt_bias    = (const float*)d_in[4];
    const float* A_log      = (const float*)d_in[5];
    const float* D_param    = (const float*)d_in[6];
    const float* norm_w     = (const float*)d_in[7];
    const float* out_proj_w = (const float*)d_in[8];
    float* out = (float*)d_out;

    float* ws   = (float*)d_ws;
    float* zbuf = ws;                                   // BLTOT*1024 f32
    float* xbc  = zbuf + (size_t)BLTOT * D_INNER;       // BLTOT*1280 f32 (pre-conv)
    float* xbcc = xbc  + (size_t)BLTOT * CONV_DIM;      // BLTOT*1280 f32 (post conv+silu)
    float* dtb  = xbcc + (size_t)BLTOT * CONV_DIM;      // BLTOT*8
    float* dtp  = dtb  + (size_t)BLTOT * NHEADS;        // BLTOT*8
    float* dAb  = dtp  + (size_t)BLTOT * NHEADS;        // BLTOT*8
    float* Pbuf = dAb  + (size_t)BLTOT * NHEADS;        // 256 floats
    float* ybuf = xbc;                // pre-conv xbc dead after K3
    float* statebuf = out;            // scratch inside d_out; K6 overwrites all

    // bf16 scratch overlaid on dead regions:
    ushort* xT    = (ushort*)xbcc;                     // 16384*512 bf16, dead after k1 (k3 overwrites later)
    ushort* Wb    = xT + (size_t)BLTOT * DIMC;         // 2432*512 bf16
    ushort* ybB   = (ushort*)xbcc;                     // 16384*1024 bf16 (xbcc dead after k4a_final)
    ushort* woutB = (ushort*)zbuf;                     // 512*1024 bf16 (zbuf dead after k5)

    k0a_xT<<<dim3(8192), dim3(256), 0, stream>>>(x, xT);
    k0b_wb<<<dim3(NPAD * DIMC / 1024), dim3(256), 0, stream>>>(in_proj_w, Wb);
    k1_mfma<<<dim3(128, 19), dim3(256), 0, stream>>>(xT, Wb, zbuf, xbc, dtb);
    k2_dt<<<dim3(512), dim3(256), 0, stream>>>(dtb, dt_bias, A_log, dtp, dAb);
    k3_conv<<<dim3(81920), dim3(256), 0, stream>>>(xbc, conv_w, conv_b, xbcc);
    k4s_state<<<dim3(2048), dim3(256), 0, stream>>>(xbcc, dtp, dAb, statebuf, Pbuf);
    k4b_prefix<<<dim3(32), dim3(256), 0, stream>>>(statebuf, Pbuf);
    k4a_final<<<dim3(2048), dim3(256), 0, stream>>>(xbcc, dtp, dAb, D_param, statebuf, ybuf);
    k5_norm<<<dim3(BLTOT), dim3(256), 0, stream>>>(ybuf, zbuf, norm_w, ybB);
    k0c_wout<<<dim3(512), dim3(256), 0, stream>>>(out_proj_w, woutB);
    k6_mfma<<<dim3(4, 128), dim3(256), 0, stream>>>(woutB, ybB, x, out);
}

// Round 6
// 413.199 us; speedup vs baseline: 11.1834x; 2.4157x over previous
//
#include <hip/hip_runtime.h>
#include <cstdint>
#include <cstddef>

#define DIMC     512
#define D_INNER  1024
#define HEADDIM  128
#define NHEADS   8
#define D_STATE  128
#define CONV_DIM 1280
#define D_IN_PROJ 2312
#define NPAD     2432
#define BSZ      4
#define LSEQ     4096
#define BLTOT    (BSZ*LSEQ)   // 16384
#define QC       64           // SSD chunk length
#define NCH      (LSEQ/QC)    // 64 chunks

typedef short bf16x8 __attribute__((ext_vector_type(8)));
typedef float f32x4  __attribute__((ext_vector_type(4)));
typedef _Float16 f16x8 __attribute__((ext_vector_type(8)));
typedef _Float16 f16x4 __attribute__((ext_vector_type(4)));

__device__ inline ushort f2bf(float f) {
    uint32_t u = __float_as_uint(f);
    uint32_t r = (u + 0x7FFFu + ((u >> 16) & 1u)) >> 16;
    return (ushort)r;
}

// ---------------- K0a: transpose + convert x [b,d,l] fp32 -> xT [b,l,d] bf16 (for k1) ----------------
__global__ __launch_bounds__(256) void k0a_xT(const float* __restrict__ x, ushort* __restrict__ xT)
{
    __shared__ float t[32][33];
    const int bx = blockIdx.x;
    const int lt = bx & 127, dt = (bx >> 7) & 15, b = bx >> 11;
    const int r = threadIdx.x >> 5, c = threadIdx.x & 31;
    #pragma unroll
    for (int i = 0; i < 4; ++i) {
        int d = dt * 32 + r + i * 8;
        t[r + i * 8][c] = x[((size_t)(b * DIMC + d) << 12) + lt * 32 + c];
    }
    __syncthreads();
    #pragma unroll
    for (int i = 0; i < 4; ++i) {
        int l = lt * 32 + r + i * 8;
        xT[((size_t)(b * LSEQ + l)) * DIMC + dt * 32 + c] = f2bf(t[c][r + i * 8]);
    }
}

// ---------------- K0b: convert + pad in_proj_w -> bf16 [2432][512] ----------------
__global__ __launch_bounds__(256) void k0b_wb(const float* __restrict__ W, ushort* __restrict__ Wb)
{
    int i4 = (blockIdx.x * 256 + threadIdx.x) * 4;
    int e = i4 >> 9;
    ushort4 o;
    if (e < D_IN_PROJ) {
        float4 v = *(const float4*)(W + (size_t)e * DIMC + (i4 & 511));
        o.x = f2bf(v.x); o.y = f2bf(v.y); o.z = f2bf(v.z); o.w = f2bf(v.w);
    } else { o.x = o.y = o.z = o.w = 0; }
    *(ushort4*)(Wb + i4) = o;
}

// ---------------- K0c: convert out_proj_w -> bf16 [512][1024] ----------------
__global__ __launch_bounds__(256) void k0c_wout(const float* __restrict__ W, ushort* __restrict__ Wb)
{
    int i4 = (blockIdx.x * 256 + threadIdx.x) * 4;
    float4 v = *(const float4*)(W + i4);
    ushort4 o;
    o.x = f2bf(v.x); o.y = f2bf(v.y); o.z = f2bf(v.z); o.w = f2bf(v.w);
    *(ushort4*)(Wb + i4) = o;
}

// ---------------- K1: in_proj GEMM, bf16 MFMA ----------------
__global__ __launch_bounds__(256) void k1_mfma(
    const ushort* __restrict__ A, const ushort* __restrict__ B,
    float* __restrict__ zbuf, _Float16* __restrict__ xbcPre, float* __restrict__ dtb)
{
    __shared__ ushort sA[128 * 32];
    __shared__ ushort sB[128 * 32];
    const int tid = threadIdx.x;
    const int lane = tid & 63;
    const int wv = tid >> 6;
    const int wm = (wv & 1) * 64, wn = (wv >> 1) * 64;
    const int m0 = blockIdx.x * 128;
    const int n0 = blockIdx.y * 128;

    f32x4 acc[4][4];
    #pragma unroll
    for (int i = 0; i < 4; ++i)
        #pragma unroll
        for (int j = 0; j < 4; ++j) acc[i][j] = (f32x4){0.f, 0.f, 0.f, 0.f};

    const int s0_ = tid, s1_ = tid + 256;
    const int r0 = s0_ >> 2, c0 = s0_ & 3, k80 = c0 ^ ((r0 >> 1) & 3);
    const int r1 = s1_ >> 2, c1 = s1_ & 3, k81 = c1 ^ ((r1 >> 1) & 3);
    const int quad = lane >> 4, col = lane & 15;

    for (int kb = 0; kb < DIMC; kb += 32) {
        int4 a0 = *(const int4*)(A + (size_t)(m0 + r0) * DIMC + kb + k80 * 8);
        int4 a1 = *(const int4*)(A + (size_t)(m0 + r1) * DIMC + kb + k81 * 8);
        int4 b0 = *(const int4*)(B + (size_t)(n0 + r0) * DIMC + kb + k80 * 8);
        int4 b1 = *(const int4*)(B + (size_t)(n0 + r1) * DIMC + kb + k81 * 8);
        __syncthreads();
        *(int4*)&sA[s0_ * 8] = a0;
        *(int4*)&sA[s1_ * 8] = a1;
        *(int4*)&sB[s0_ * 8] = b0;
        *(int4*)&sB[s1_ * 8] = b1;
        __syncthreads();
        bf16x8 af[4], bf_[4];
        #pragma unroll
        for (int mi = 0; mi < 4; ++mi) {
            int m = wm + mi * 16 + col;
            int ch = quad ^ ((m >> 1) & 3);
            af[mi] = *(const bf16x8*)&sA[m * 32 + ch * 8];
        }
        #pragma unroll
        for (int ni = 0; ni < 4; ++ni) {
            int n = wn + ni * 16 + col;
            int ch = quad ^ ((n >> 1) & 3);
            bf_[ni] = *(const bf16x8*)&sB[n * 32 + ch * 8];
        }
        #pragma unroll
        for (int mi = 0; mi < 4; ++mi)
            #pragma unroll
            for (int ni = 0; ni < 4; ++ni)
                acc[mi][ni] = __builtin_amdgcn_mfma_f32_16x16x32_bf16(af[mi], bf_[ni], acc[mi][ni], 0, 0, 0);
    }

    #pragma unroll
    for (int mi = 0; mi < 4; ++mi) {
        #pragma unroll
        for (int ni = 0; ni < 4; ++ni) {
            int e = n0 + wn + ni * 16 + col;
            #pragma unroll
            for (int reg = 0; reg < 4; ++reg) {
                int m = m0 + wm + mi * 16 + quad * 4 + reg;
                float v = acc[mi][ni][reg];
                if (e < D_INNER)                  zbuf[(size_t)m * D_INNER + e] = v;
                else if (e < D_INNER + CONV_DIM)  xbcPre[(size_t)m * CONV_DIM + (e - D_INNER)] = (_Float16)v;
                else if (e < D_IN_PROJ)           dtb[(size_t)m * NHEADS + (e - (D_INNER + CONV_DIM))] = v;
            }
        }
    }
}

// ---------------- K2: softplus(dt + bias) -> dtp; ldA = dtp * (-exp(A_log)) ----------------
__global__ __launch_bounds__(256) void k2_dt(
    const float* __restrict__ dtb, const float* __restrict__ dt_bias,
    const float* __restrict__ A_log, float* __restrict__ dtp, float* __restrict__ ldA)
{
    int idx = blockIdx.x * 256 + threadIdx.x;
    if (idx >= BLTOT * NHEADS) return;
    int h = idx & 7;
    float v = dtb[idx] + dt_bias[h];
    float sp = (v > 20.f) ? v : log1pf(expf(v));
    dtp[idx] = sp;
    ldA[idx] = sp * (-expf(A_log[h]));
}

// ---------------- K3x: conv+silu channels 0..1023 -> xsT[b][p][t] f16 (transposed) ----------------
__global__ __launch_bounds__(256) void k3x(
    const _Float16* __restrict__ xbcPre, const float* __restrict__ cw,
    const float* __restrict__ cb, _Float16* __restrict__ xsT)
{
    __shared__ _Float16 tT[32][36];
    const int bx = blockIdx.x;
    const int ct = bx & 31, tt = (bx >> 5) & 127, b = bx >> 12;
    const int t0 = tt * 32, c0 = ct * 32;
    const int tid = threadIdx.x;
    const int tq = tid >> 3, cg = tid & 7;
    const int t = t0 + tq;
    const int c = c0 + cg * 4;
    const int m = b * LSEQ + t;

    float acc[4] = {cb[c], cb[c + 1], cb[c + 2], cb[c + 3]};
    #pragma unroll
    for (int j = 0; j < 4; ++j) {
        if (t - j >= 0) {
            f16x4 xv = *(const f16x4*)&xbcPre[(size_t)(m - j) * CONV_DIM + c];
            #pragma unroll
            for (int i = 0; i < 4; ++i)
                acc[i] = fmaf((float)xv[i], cw[(c + i) * 4 + (3 - j)], acc[i]);
        }
    }
    #pragma unroll
    for (int i = 0; i < 4; ++i) {
        float s = acc[i] / (1.f + expf(-acc[i]));
        tT[cg * 4 + i][tq] = (_Float16)s;
    }
    __syncthreads();
    const int r = tid >> 3, g = tid & 7;
    f16x4 o = *(const f16x4*)&tT[r][g * 4];
    *(f16x4*)&xsT[((size_t)b * D_INNER + c0 + r) * LSEQ + t0 + g * 4] = o;
}

// ---------------- K3bc: conv+silu channels 1024..1279 -> bcNat f16 + BT f16 ----------------
__global__ __launch_bounds__(256) void k3bc(
    const _Float16* __restrict__ xbcPre, const float* __restrict__ cw,
    const float* __restrict__ cb, _Float16* __restrict__ bcNat, _Float16* __restrict__ BT)
{
    __shared__ _Float16 tT[32][36];
    const int bx = blockIdx.x;
    const int ct = bx & 7, tt = (bx >> 3) & 127, b = bx >> 10;
    const int t0 = tt * 32, c0 = ct * 32;
    const int tid = threadIdx.x;
    const int tq = tid >> 3, cg = tid & 7;
    const int t = t0 + tq;
    const int ca = 1024 + c0 + cg * 4;
    const int m = b * LSEQ + t;

    float acc[4] = {cb[ca], cb[ca + 1], cb[ca + 2], cb[ca + 3]};
    #pragma unroll
    for (int j = 0; j < 4; ++j) {
        if (t - j >= 0) {
            f16x4 xv = *(const f16x4*)&xbcPre[(size_t)(m - j) * CONV_DIM + ca];
            #pragma unroll
            for (int i = 0; i < 4; ++i)
                acc[i] = fmaf((float)xv[i], cw[(ca + i) * 4 + (3 - j)], acc[i]);
        }
    }
    f16x4 nat;
    #pragma unroll
    for (int i = 0; i < 4; ++i) {
        float s = acc[i] / (1.f + expf(-acc[i]));
        nat[i] = (_Float16)s;
        tT[cg * 4 + i][tq] = nat[i];
    }
    *(f16x4*)&bcNat[(size_t)m * 256 + c0 + cg * 4] = nat;
    if (ct < 4) {   // B channels: also transposed
        __syncthreads();
        const int r = tid >> 3, g = tid & 7;
        f16x4 o = *(const f16x4*)&tT[r][g * 4];
        *(f16x4*)&BT[((size_t)b * D_STATE + c0 + r) * LSEQ + t0 + g * 4] = o;
    }
}

// ---------------- K4aA: per-chunk local state GEMM: ST[p][n] = sum_tau w_tau X[tau][p] B[tau][n] ----------------
__global__ __launch_bounds__(256) void k4aA(
    const _Float16* __restrict__ xsT, const _Float16* __restrict__ BT,
    const float* __restrict__ dtp, const float* __restrict__ ldA,
    _Float16* __restrict__ ST, float* __restrict__ Pbuf)
{
    __shared__ char smem[128 * 72 * 2 * 2 + 512];
    _Float16* sXTs = (_Float16*)smem;
    _Float16* sBT  = sXTs + 128 * 72;
    float* sW = (float*)(sBT + 128 * 72);
    _Float16* sOut = sXTs;   // reuse for repack

    const int tid = threadIdx.x;
    const int lane = tid & 63;
    const int wv = tid >> 6;
    const int quad = lane >> 4, l15 = lane & 15;
    const int c = blockIdx.x & 63;
    const int h = (blockIdx.x >> 6) & 7;
    const int b = blockIdx.x >> 9;
    const int bh = b * NHEADS + h;
    const size_t mbase = (size_t)b * LSEQ + c * QC;

    if (tid < 64) {
        size_t gi = (mbase + tid) * NHEADS + h;
        float ld = ldA[gi];
        float dtv = dtp[gi];
        float cum = ld;
        #pragma unroll
        for (int off = 1; off < 64; off <<= 1) {
            float v = __shfl_up(cum, off);
            if (tid >= off) cum += v;
        }
        float cum63 = __shfl(cum, 63);
        sW[tid] = expf(cum63 - cum) * dtv;
        if (tid == 63) Pbuf[bh * NCH + c] = expf(cum63);
    }
    __syncthreads();

    // stage XTs (scaled) and BT
    #pragma unroll
    for (int k = 0; k < 4; ++k) {
        int idx = k * 256 + tid;
        int row = idx >> 3, g = idx & 7;
        int t0 = g * 8;
        f16x8 hv = *(const f16x8*)&xsT[((size_t)b * D_INNER + h * HEADDIM + row) * LSEQ + c * QC + t0];
        f16x8 sv;
        #pragma unroll
        for (int j = 0; j < 8; ++j) sv[j] = (_Float16)((float)hv[j] * sW[t0 + j]);
        *(f16x8*)&sXTs[row * 72 + t0] = sv;
        int4 bv = *(const int4*)&BT[((size_t)b * D_STATE + row) * LSEQ + c * QC + t0];
        *(int4*)&sBT[row * 72 + t0] = bv;
    }
    __syncthreads();

    f32x4 acc[2][8];
    #pragma unroll
    for (int i = 0; i < 2; ++i)
        #pragma unroll
        for (int j = 0; j < 8; ++j) acc[i][j] = (f32x4){0.f, 0.f, 0.f, 0.f};

    #pragma unroll
    for (int kk = 0; kk < 2; ++kk) {
        f16x8 af[2];
        #pragma unroll
        for (int mi = 0; mi < 2; ++mi)
            af[mi] = *(const f16x8*)&sXTs[(wv * 32 + mi * 16 + l15) * 72 + kk * 32 + quad * 8];
        #pragma unroll
        for (int ni = 0; ni < 8; ++ni) {
            f16x8 bf_ = *(const f16x8*)&sBT[(ni * 16 + l15) * 72 + kk * 32 + quad * 8];
            #pragma unroll
            for (int mi = 0; mi < 2; ++mi)
                acc[mi][ni] = __builtin_amdgcn_mfma_f32_16x16x32_f16(af[mi], bf_, acc[mi][ni], 0, 0, 0);
        }
    }
    __syncthreads();
    // repack acc -> sOut[p][n] (stride 136)
    #pragma unroll
    for (int mi = 0; mi < 2; ++mi)
        #pragma unroll
        for (int ni = 0; ni < 8; ++ni)
            #pragma unroll
            for (int reg = 0; reg < 4; ++reg) {
                int p = wv * 32 + mi * 16 + quad * 4 + reg;
                int n = ni * 16 + l15;
                sOut[p * 136 + n] = (_Float16)acc[mi][ni][reg];
            }
    __syncthreads();
    _Float16* stg = ST + ((size_t)bh * NCH + c) * (HEADDIM * D_STATE);
    #pragma unroll
    for (int k = 0; k < 8; ++k) {
        int idx = k * 256 + tid;
        int row = idx >> 4, g = idx & 15;
        int4 v = *(const int4*)&sOut[row * 136 + g * 8];
        *(int4*)&stg[row * 128 + g * 8] = v;
    }
}

// ---------------- K4bB: 64-chunk state prefix (in place): S_local -> s_init ----------------
__global__ __launch_bounds__(256) void k4bB(_Float16* __restrict__ ST, const float* __restrict__ Pbuf)
{
    __shared__ float sp_[NCH];
    const int bh = blockIdx.x >> 4;
    const int seg = blockIdx.x & 15;
    const int tid = threadIdx.x;
    if (tid < NCH) sp_[tid] = Pbuf[bh * NCH + tid];
    __syncthreads();
    const int e = seg * 1024 + tid * 4;
    float r0 = 0.f, r1 = 0.f, r2 = 0.f, r3 = 0.f;
    for (int c = 0; c < NCH; ++c) {
        _Float16* ptr = ST + ((size_t)bh * NCH + c) * (HEADDIM * D_STATE) + e;
        f16x4 v = *(const f16x4*)ptr;
        float f0 = (float)v[0], f1 = (float)v[1], f2 = (float)v[2], f3 = (float)v[3];
        f16x4 o; o[0] = (_Float16)r0; o[1] = (_Float16)r1; o[2] = (_Float16)r2; o[3] = (_Float16)r3;
        *(f16x4*)ptr = o;
        float P = sp_[c];
        r0 = fmaf(r0, P, f0); r1 = fmaf(r1, P, f1);
        r2 = fmaf(r2, P, f2); r3 = fmaf(r3, P, f3);
    }
}

// ---------------- K4cC: per-chunk y via SSD GEMMs ----------------
__global__ __launch_bounds__(256) void k4cC(
    const _Float16* __restrict__ bcNat, const _Float16* __restrict__ xsT,
    const _Float16* __restrict__ sinit, const float* __restrict__ dtp,
    const float* __restrict__ ldA, const float* __restrict__ Dp,
    _Float16* __restrict__ yB)
{
    __shared__ char smem[(64*136 + 64*136 + 128*72 + 4*16*72) * 2 + 640];
    _Float16* sC  = (_Float16*)smem;          // 64 x 136
    _Float16* sB  = sC + 64 * 136;            // 64 x 136
    _Float16* sXT = sB + 64 * 136;            // 128 x 72
    _Float16* sM  = sXT + 128 * 72;           // 4 waves x 16 x 72
    float* scum = (float*)(sM + 4 * 16 * 72); // 64
    float* sdt  = scum + 64;                  // 64
    _Float16* sIni = sB;                      // 128 x 136 overlays sB+sXT
    _Float16* sY  = sC;                       // 64 x 136 overlays sC

    const int tid = threadIdx.x;
    const int lane = tid & 63;
    const int wv = tid >> 6;
    const int quad = lane >> 4, l15 = lane & 15;
    const int c = blockIdx.x & 63;
    const int h = (blockIdx.x >> 6) & 7;
    const int b = blockIdx.x >> 9;
    const int bh = b * NHEADS + h;
    const size_t mbase = (size_t)b * LSEQ + c * QC;
    const float Dh = Dp[h];

    if (tid < 64) {
        size_t gi = (mbase + tid) * NHEADS + h;
        float ld = ldA[gi];
        float dtv = dtp[gi];
        float cum = ld;
        #pragma unroll
        for (int off = 1; off < 64; off <<= 1) {
            float v = __shfl_up(cum, off);
            if (tid >= off) cum += v;
        }
        scum[tid] = cum;
        sdt[tid] = dtv;
    }
    // stage B, C natural (64x128 each) and XT (128x64)
    #pragma unroll
    for (int k = 0; k < 4; ++k) {
        int idx = k * 256 + tid;
        int t = idx >> 4, g = idx & 15;
        const _Float16* row = bcNat + (mbase + t) * 256;
        *(int4*)&sB[t * 136 + g * 8] = *(const int4*)&row[g * 8];
        *(int4*)&sC[t * 136 + g * 8] = *(const int4*)&row[128 + g * 8];
        int idx2 = k * 256 + tid;
        int p = idx2 >> 3, g2 = idx2 & 7;
        *(int4*)&sXT[p * 72 + g2 * 8] =
            *(const int4*)&xsT[((size_t)b * D_INNER + h * HEADDIM + p) * LSEQ + c * QC + g2 * 8];
    }
    __syncthreads();

    // G = C @ B^T : wave wv computes rows [wv*16, +16) x 64 cols, K = 128
    f32x4 g[4];
    #pragma unroll
    for (int j = 0; j < 4; ++j) g[j] = (f32x4){0.f, 0.f, 0.f, 0.f};
    #pragma unroll
    for (int kk = 0; kk < 4; ++kk) {
        f16x8 af = *(const f16x8*)&sC[(wv * 16 + l15) * 136 + kk * 32 + quad * 8];
        #pragma unroll
        for (int tt = 0; tt < 4; ++tt) {
            f16x8 bf_ = *(const f16x8*)&sB[(tt * 16 + l15) * 136 + kk * 32 + quad * 8];
            g[tt] = __builtin_amdgcn_mfma_f32_16x16x32_f16(af, bf_, g[tt], 0, 0, 0);
        }
    }
    // mask -> M (f16, per-wave region)
    _Float16* sMw = sM + wv * 16 * 72;
    #pragma unroll
    for (int tt = 0; tt < 4; ++tt) {
        int tau = tt * 16 + l15;
        #pragma unroll
        for (int reg = 0; reg < 4; ++reg) {
            int trow = quad * 4 + reg;
            int tglob = wv * 16 + trow;
            float mval;
            if (tau > tglob) mval = 0.f;
            else if (tau == tglob) mval = g[tt][reg] * sdt[tau] + Dh;
            else mval = g[tt][reg] * expf(scum[tglob] - scum[tau]) * sdt[tau];
            sMw[trow * 72 + tau] = (_Float16)mval;
        }
    }
    asm volatile("s_waitcnt lgkmcnt(0)" ::: "memory");

    // Y1 = M @ X^T : rows = wave's 16 t, cols = 128 p, K = 64
    f32x4 y[8];
    #pragma unroll
    for (int j = 0; j < 8; ++j) y[j] = (f32x4){0.f, 0.f, 0.f, 0.f};
    #pragma unroll
    for (int kk = 0; kk < 2; ++kk) {
        f16x8 af = *(const f16x8*)&sMw[l15 * 72 + kk * 32 + quad * 8];
        #pragma unroll
        for (int pi = 0; pi < 8; ++pi) {
            f16x8 bf_ = *(const f16x8*)&sXT[(pi * 16 + l15) * 72 + kk * 32 + quad * 8];
            y[pi] = __builtin_amdgcn_mfma_f32_16x16x32_f16(af, bf_, y[pi], 0, 0, 0);
        }
    }
    __syncthreads();
    // stage s_init (128 x 128) over sB..sXT
    {
        const _Float16* sg = sinit + ((size_t)bh * NCH + c) * (HEADDIM * D_STATE);
        #pragma unroll
        for (int k = 0; k < 8; ++k) {
            int idx = k * 256 + tid;
            int p = idx >> 4, gg = idx & 15;
            *(int4*)&sIni[p * 136 + gg * 8] = *(const int4*)&sg[p * 128 + gg * 8];
        }
    }
    __syncthreads();
    // Y2 += (e^cum * C) @ s_init^T : K = 128
    {
        float ea = expf(scum[wv * 16 + l15]);
        #pragma unroll
        for (int kk = 0; kk < 4; ++kk) {
            f16x8 cf = *(const f16x8*)&sC[(wv * 16 + l15) * 136 + kk * 32 + quad * 8];
            f16x8 af;
            #pragma unroll
            for (int j = 0; j < 8; ++j) af[j] = (_Float16)((float)cf[j] * ea);
            #pragma unroll
            for (int pi = 0; pi < 8; ++pi) {
                f16x8 bf_ = *(const f16x8*)&sIni[(pi * 16 + l15) * 136 + kk * 32 + quad * 8];
                y[pi] = __builtin_amdgcn_mfma_f32_16x16x32_f16(af, bf_, y[pi], 0, 0, 0);
            }
        }
    }
    __syncthreads();
    // epilogue: y -> sY (wave-local rows) -> global
    #pragma unroll
    for (int pi = 0; pi < 8; ++pi)
        #pragma unroll
        for (int reg = 0; reg < 4; ++reg) {
            int trow = wv * 16 + quad * 4 + reg;
            int p = pi * 16 + l15;
            sY[trow * 136 + p] = (_Float16)y[pi][reg];
        }
    __syncthreads();
    #pragma unroll
    for (int k = 0; k < 4; ++k) {
        int idx = k * 256 + tid;
        int t = idx >> 4, gg = idx & 15;
        int4 v = *(const int4*)&sY[t * 136 + gg * 8];
        *(int4*)&yB[(mbase + t) * D_INNER + h * HEADDIM + gg * 8] = v;
    }
}

// ---------------- K5: y *= silu(z); RMSNorm * norm_w -> bf16 (in place over yB) ----------------
__global__ __launch_bounds__(256) void k5_norm(
    const _Float16* __restrict__ yB, const float* __restrict__ zbuf,
    const float* __restrict__ nw, ushort* __restrict__ ybB)
{
    const int m = blockIdx.x;
    const int tid = threadIdx.x;
    const size_t off = (size_t)m * D_INNER + tid * 4;
    f16x4 yv = *(const f16x4*)&yB[off];
    float4 zv = *(const float4*)(zbuf + off);
    float4 gv;
    gv.x = (float)yv[0] * (zv.x / (1.f + expf(-zv.x)));
    gv.y = (float)yv[1] * (zv.y / (1.f + expf(-zv.y)));
    gv.z = (float)yv[2] * (zv.z / (1.f + expf(-zv.z)));
    gv.w = (float)yv[3] * (zv.w / (1.f + expf(-zv.w)));
    float ss = gv.x*gv.x + gv.y*gv.y + gv.z*gv.z + gv.w*gv.w;
    #pragma unroll
    for (int mask = 1; mask <= 32; mask <<= 1) ss += __shfl_xor(ss, mask);
    __shared__ float red[4];
    if ((tid & 63) == 0) red[tid >> 6] = ss;
    __syncthreads();
    float tot = red[0] + red[1] + red[2] + red[3];
    float scale = rsqrtf(tot * (1.f / 1024.f) + 1e-5f);
    float4 w4 = *(const float4*)(nw + tid * 4);
    ushort4 ob;
    ob.x = f2bf(gv.x * scale * w4.x);
    ob.y = f2bf(gv.y * scale * w4.y);
    ob.z = f2bf(gv.z * scale * w4.z);
    ob.w = f2bf(gv.w * scale * w4.w);
    *(ushort4*)(ybB + off) = ob;
}

// ---------------- K6: out_proj GEMM bf16 MFMA + residual, transposed store ----------------
__global__ __launch_bounds__(256) void k6_mfma(
    const ushort* __restrict__ A, const ushort* __restrict__ B,
    const float* __restrict__ x, float* __restrict__ out)
{
    __shared__ ushort sA[128 * 32];
    __shared__ ushort sB[128 * 32];
    const int tid = threadIdx.x;
    const int lane = tid & 63;
    const int wv = tid >> 6;
    const int wm = (wv & 1) * 64, wn = (wv >> 1) * 64;
    const int m0 = blockIdx.x * 128;
    const int n0 = blockIdx.y * 128;

    f32x4 acc[4][4];
    #pragma unroll
    for (int i = 0; i < 4; ++i)
        #pragma unroll
        for (int j = 0; j < 4; ++j) acc[i][j] = (f32x4){0.f, 0.f, 0.f, 0.f};

    const int s0_ = tid, s1_ = tid + 256;
    const int r0 = s0_ >> 2, c0 = s0_ & 3, k80 = c0 ^ ((r0 >> 1) & 3);
    const int r1 = s1_ >> 2, c1 = s1_ & 3, k81 = c1 ^ ((r1 >> 1) & 3);
    const int quad = lane >> 4, col = lane & 15;

    for (int kb = 0; kb < D_INNER; kb += 32) {
        int4 a0 = *(const int4*)(A + (size_t)(m0 + r0) * D_INNER + kb + k80 * 8);
        int4 a1 = *(const int4*)(A + (size_t)(m0 + r1) * D_INNER + kb + k81 * 8);
        int4 b0 = *(const int4*)(B + (size_t)(n0 + r0) * D_INNER + kb + k80 * 8);
        int4 b1 = *(const int4*)(B + (size_t)(n0 + r1) * D_INNER + kb + k81 * 8);
        __syncthreads();
        *(int4*)&sA[s0_ * 8] = a0;
        *(int4*)&sA[s1_ * 8] = a1;
        *(int4*)&sB[s0_ * 8] = b0;
        *(int4*)&sB[s1_ * 8] = b1;
        __syncthreads();
        bf16x8 af[4], bf_[4];
        #pragma unroll
        for (int mi = 0; mi < 4; ++mi) {
            int m = wm + mi * 16 + col;
            int ch = quad ^ ((m >> 1) & 3);
            af[mi] = *(const bf16x8*)&sA[m * 32 + ch * 8];
        }
        #pragma unroll
        for (int ni = 0; ni < 4; ++ni) {
            int n = wn + ni * 16 + col;
            int ch = quad ^ ((n >> 1) & 3);
            bf_[ni] = *(const bf16x8*)&sB[n * 32 + ch * 8];
        }
        #pragma unroll
        for (int mi = 0; mi < 4; ++mi)
            #pragma unroll
            for (int ni = 0; ni < 4; ++ni)
                acc[mi][ni] = __builtin_amdgcn_mfma_f32_16x16x32_bf16(af[mi], bf_[ni], acc[mi][ni], 0, 0, 0);
    }

    #pragma unroll
    for (int mi = 0; mi < 4; ++mi) {
        #pragma unroll
        for (int ni = 0; ni < 4; ++ni) {
            int mm = n0 + wn + ni * 16 + col;
            int b = mm >> 12, l = mm & 4095;
            #pragma unroll
            for (int reg = 0; reg < 4; ++reg) {
                int d = m0 + wm + mi * 16 + quad * 4 + reg;
                size_t o = ((size_t)(b * DIMC + d) << 12) + l;
                out[o] = acc[mi][ni][reg] + x[o];
            }
        }
    }
}

extern "C" void kernel_launch(void* const* d_in, const int* in_sizes, int n_in,
                              void* d_out, int out_size, void* d_ws, size_t ws_size,
                              hipStream_t stream) {
    const float* x          = (const float*)d_in[0];
    const float* in_proj_w  = (const float*)d_in[1];
    const float* conv_w     = (const float*)d_in[2];
    const float* conv_b     = (const float*)d_in[3];
    const float* dt_bias    = (const float*)d_in[4];
    const float* A_log      = (const float*)d_in[5];
    const float* D_param    = (const float*)d_in[6];
    const float* norm_w     = (const float*)d_in[7];
    const float* out_proj_w = (const float*)d_in[8];
    float* out = (float*)d_out;

    float* ws = (float*)d_ws;
    float* zbuf = ws;                                      // 16,777,216 f32
    float* regB = zbuf + (size_t)16777216;                 // 10,485,760 f32
    _Float16* xbcPre = (_Float16*)regB;                    // 16384x1280 f16
    _Float16* yB     = (_Float16*)regB;                    // 16384x1024 f16 (after k3)
    float* dtb  = regB + (size_t)10485760;                 // 131072
    float* dtp  = dtb + 131072;
    float* ldA  = dtp + 131072;
    float* Pbuf = ldA + 131072;                            // 2048
    float* regD = Pbuf + 2048;                             // 16,777,216 f32
    ushort* xT_k1 = (ushort*)regD;                         // 16384x512 bf16
    ushort* Wb    = xT_k1 + (size_t)BLTOT * DIMC;          // 2432x512 bf16
    _Float16* ST  = (_Float16*)regD;                       // 32x64x128x128 f16 (after k1)
    float* regE = regD + (size_t)16777216;
    _Float16* xsT   = (_Float16*)regE;                     // 4x1024x4096 f16
    _Float16* BT    = xsT + (size_t)BSZ * D_INNER * LSEQ;  // 4x128x4096 f16
    _Float16* bcNat = BT + (size_t)BSZ * D_STATE * LSEQ;   // 16384x256 f16
    ushort* woutB = (ushort*)zbuf;                         // after k5

    k0a_xT<<<dim3(8192), dim3(256), 0, stream>>>(x, xT_k1);
    k0b_wb<<<dim3(NPAD * DIMC / 1024), dim3(256), 0, stream>>>(in_proj_w, Wb);
    k1_mfma<<<dim3(128, 19), dim3(256), 0, stream>>>(xT_k1, Wb, zbuf, xbcPre, dtb);
    k2_dt<<<dim3(512), dim3(256), 0, stream>>>(dtb, dt_bias, A_log, dtp, ldA);
    k3x<<<dim3(16384), dim3(256), 0, stream>>>(xbcPre, conv_w, conv_b, xsT);
    k3bc<<<dim3(4096), dim3(256), 0, stream>>>(xbcPre, conv_w, conv_b, bcNat, BT);
    k4aA<<<dim3(2048), dim3(256), 0, stream>>>(xsT, BT, dtp, ldA, ST, Pbuf);
    k4bB<<<dim3(512), dim3(256), 0, stream>>>(ST, Pbuf);
    k4cC<<<dim3(2048), dim3(256), 0, stream>>>(bcNat, xsT, ST, dtp, ldA, D_param, yB);
    k5_norm<<<dim3(BLTOT), dim3(256), 0, stream>>>(yB, zbuf, norm_w, (ushort*)yB);
    k0c_wout<<<dim3(512), dim3(256), 0, stream>>>(out_proj_w, woutB);
    k6_mfma<<<dim3(4, 128), dim3(256), 0, stream>>>(woutB, (ushort*)yB, x, out);
}

// Round 7
// 398.307 us; speedup vs baseline: 11.6015x; 1.0374x over previous
//
#include <hip/hip_runtime.h>
#include <cstdint>
#include <cstddef>

#define DIMC     512
#define D_INNER  1024
#define HEADDIM  128
#define NHEADS   8
#define D_STATE  128
#define CONV_DIM 1280
#define D_IN_PROJ 2312
#define NPAD     2432
#define BSZ      4
#define LSEQ     4096
#define BLTOT    (BSZ*LSEQ)   // 16384
#define QC       64           // SSD chunk length
#define NCH      (LSEQ/QC)    // 64 chunks

typedef short bf16x8 __attribute__((ext_vector_type(8)));
typedef float f32x4  __attribute__((ext_vector_type(4)));
typedef _Float16 f16x8 __attribute__((ext_vector_type(8)));
typedef _Float16 f16x4 __attribute__((ext_vector_type(4)));

__device__ inline ushort f2bf(float f) {
    uint32_t u = __float_as_uint(f);
    uint32_t r = (u + 0x7FFFu + ((u >> 16) & 1u)) >> 16;
    return (ushort)r;
}

// async global->LDS, 16B per lane; lds base must be wave-uniform
__device__ __forceinline__ void gload_lds16(const void* g, void* l) {
    __builtin_amdgcn_global_load_lds(
        (const __attribute__((address_space(1))) void*)g,
        (__attribute__((address_space(3))) void*)l,
        16, 0, 0);
}

// ---------------- K0a: transpose + convert x [b,d,l] fp32 -> xT [b,l,d] bf16 (for k1) ----------------
__global__ __launch_bounds__(256) void k0a_xT(const float* __restrict__ x, ushort* __restrict__ xT)
{
    __shared__ float t[32][33];
    const int bx = blockIdx.x;
    const int lt = bx & 127, dt = (bx >> 7) & 15, b = bx >> 11;
    const int r = threadIdx.x >> 5, c = threadIdx.x & 31;
    #pragma unroll
    for (int i = 0; i < 4; ++i) {
        int d = dt * 32 + r + i * 8;
        t[r + i * 8][c] = x[((size_t)(b * DIMC + d) << 12) + lt * 32 + c];
    }
    __syncthreads();
    #pragma unroll
    for (int i = 0; i < 4; ++i) {
        int l = lt * 32 + r + i * 8;
        xT[((size_t)(b * LSEQ + l)) * DIMC + dt * 32 + c] = f2bf(t[c][r + i * 8]);
    }
}

// ---------------- K0b: convert + pad in_proj_w -> bf16 [2432][512] ----------------
__global__ __launch_bounds__(256) void k0b_wb(const float* __restrict__ W, ushort* __restrict__ Wb)
{
    int i4 = (blockIdx.x * 256 + threadIdx.x) * 4;
    int e = i4 >> 9;
    ushort4 o;
    if (e < D_IN_PROJ) {
        float4 v = *(const float4*)(W + (size_t)e * DIMC + (i4 & 511));
        o.x = f2bf(v.x); o.y = f2bf(v.y); o.z = f2bf(v.z); o.w = f2bf(v.w);
    } else { o.x = o.y = o.z = o.w = 0; }
    *(ushort4*)(Wb + i4) = o;
}

// ---------------- K0c: convert out_proj_w -> bf16 [512][1024] ----------------
__global__ __launch_bounds__(256) void k0c_wout(const float* __restrict__ W, ushort* __restrict__ Wb)
{
    int i4 = (blockIdx.x * 256 + threadIdx.x) * 4;
    float4 v = *(const float4*)(W + i4);
    ushort4 o;
    o.x = f2bf(v.x); o.y = f2bf(v.y); o.z = f2bf(v.z); o.w = f2bf(v.w);
    *(ushort4*)(Wb + i4) = o;
}

// ---------------- K1: in_proj GEMM, bf16 MFMA, global_load_lds staging ----------------
__global__ __launch_bounds__(256) void k1_mfma(
    const ushort* __restrict__ A, const ushort* __restrict__ B,
    _Float16* __restrict__ zh, _Float16* __restrict__ xbcPre, float* __restrict__ dtb)
{
    __shared__ ushort sA[128 * 32];
    __shared__ ushort sB[128 * 32];
    const int tid = threadIdx.x;
    const int lane = tid & 63;
    const int wv = tid >> 6;
    const int wm = (wv & 1) * 64, wn = (wv >> 1) * 64;
    const int m0 = blockIdx.x * 128;
    const int n0 = blockIdx.y * 128;

    f32x4 acc[4][4];
    #pragma unroll
    for (int i = 0; i < 4; ++i)
        #pragma unroll
        for (int j = 0; j < 4; ++j) acc[i][j] = (f32x4){0.f, 0.f, 0.f, 0.f};

    // slot s holds row r=s>>2, k-chunk k8=(s&3)^((r>>1)&3); slots: tid and tid+256
    const int r0 = tid >> 2, c0 = tid & 3, k80 = c0 ^ ((r0 >> 1) & 3);
    const int s1_ = tid + 256;
    const int r1 = s1_ >> 2, c1 = s1_ & 3, k81 = c1 ^ ((r1 >> 1) & 3);
    const int quad = lane >> 4, col = lane & 15;
    // wave-uniform LDS bases (ushort units): slot*8
    ushort* lA0 = sA + (size_t)(wv * 64) * 8;
    ushort* lA1 = sA + (size_t)(256 + wv * 64) * 8;
    ushort* lB0 = sB + (size_t)(wv * 64) * 8;
    ushort* lB1 = sB + (size_t)(256 + wv * 64) * 8;

    for (int kb = 0; kb < DIMC; kb += 32) {
        gload_lds16(A + (size_t)(m0 + r0) * DIMC + kb + k80 * 8, lA0);
        gload_lds16(A + (size_t)(m0 + r1) * DIMC + kb + k81 * 8, lA1);
        gload_lds16(B + (size_t)(n0 + r0) * DIMC + kb + k80 * 8, lB0);
        gload_lds16(B + (size_t)(n0 + r1) * DIMC + kb + k81 * 8, lB1);
        __syncthreads();
        bf16x8 af[4], bf_[4];
        #pragma unroll
        for (int mi = 0; mi < 4; ++mi) {
            int m = wm + mi * 16 + col;
            int ch = quad ^ ((m >> 1) & 3);
            af[mi] = *(const bf16x8*)&sA[m * 32 + ch * 8];
        }
        #pragma unroll
        for (int ni = 0; ni < 4; ++ni) {
            int n = wn + ni * 16 + col;
            int ch = quad ^ ((n >> 1) & 3);
            bf_[ni] = *(const bf16x8*)&sB[n * 32 + ch * 8];
        }
        #pragma unroll
        for (int mi = 0; mi < 4; ++mi)
            #pragma unroll
            for (int ni = 0; ni < 4; ++ni)
                acc[mi][ni] = __builtin_amdgcn_mfma_f32_16x16x32_bf16(af[mi], bf_[ni], acc[mi][ni], 0, 0, 0);
        __syncthreads();
    }

    #pragma unroll
    for (int mi = 0; mi < 4; ++mi) {
        #pragma unroll
        for (int ni = 0; ni < 4; ++ni) {
            int e = n0 + wn + ni * 16 + col;
            #pragma unroll
            for (int reg = 0; reg < 4; ++reg) {
                int m = m0 + wm + mi * 16 + quad * 4 + reg;
                float v = acc[mi][ni][reg];
                if (e < D_INNER)                  zh[(size_t)m * D_INNER + e] = (_Float16)v;
                else if (e < D_INNER + CONV_DIM)  xbcPre[(size_t)m * CONV_DIM + (e - D_INNER)] = (_Float16)v;
                else if (e < D_IN_PROJ)           dtb[(size_t)m * NHEADS + (e - (D_INNER + CONV_DIM))] = v;
            }
        }
    }
}

// ---------------- K2: softplus(dt + bias) -> dtp; ldA = dtp * (-exp(A_log)) ----------------
__global__ __launch_bounds__(256) void k2_dt(
    const float* __restrict__ dtb, const float* __restrict__ dt_bias,
    const float* __restrict__ A_log, float* __restrict__ dtp, float* __restrict__ ldA)
{
    int idx = blockIdx.x * 256 + threadIdx.x;
    if (idx >= BLTOT * NHEADS) return;
    int h = idx & 7;
    float v = dtb[idx] + dt_bias[h];
    float sp = (v > 20.f) ? v : log1pf(expf(v));
    dtp[idx] = sp;
    ldA[idx] = sp * (-expf(A_log[h]));
}

// ---------------- K3x: conv+silu channels 0..1023 -> xsT[b][p][t] f16 (transposed) ----------------
__global__ __launch_bounds__(256) void k3x(
    const _Float16* __restrict__ xbcPre, const float* __restrict__ cw,
    const float* __restrict__ cb, _Float16* __restrict__ xsT)
{
    __shared__ _Float16 tT[32][36];
    const int bx = blockIdx.x;
    const int ct = bx & 31, tt = (bx >> 5) & 127, b = bx >> 12;
    const int t0 = tt * 32, c0 = ct * 32;
    const int tid = threadIdx.x;
    const int tq = tid >> 3, cg = tid & 7;
    const int t = t0 + tq;
    const int c = c0 + cg * 4;
    const int m = b * LSEQ + t;

    float acc[4] = {cb[c], cb[c + 1], cb[c + 2], cb[c + 3]};
    #pragma unroll
    for (int j = 0; j < 4; ++j) {
        if (t - j >= 0) {
            f16x4 xv = *(const f16x4*)&xbcPre[(size_t)(m - j) * CONV_DIM + c];
            #pragma unroll
            for (int i = 0; i < 4; ++i)
                acc[i] = fmaf((float)xv[i], cw[(c + i) * 4 + (3 - j)], acc[i]);
        }
    }
    #pragma unroll
    for (int i = 0; i < 4; ++i) {
        float s = acc[i] / (1.f + expf(-acc[i]));
        tT[cg * 4 + i][tq] = (_Float16)s;
    }
    __syncthreads();
    const int r = tid >> 3, g = tid & 7;
    f16x4 o = *(const f16x4*)&tT[r][g * 4];
    *(f16x4*)&xsT[((size_t)b * D_INNER + c0 + r) * LSEQ + t0 + g * 4] = o;
}

// ---------------- K3bc: conv+silu channels 1024..1279 -> bcNat f16 + BT f16 ----------------
__global__ __launch_bounds__(256) void k3bc(
    const _Float16* __restrict__ xbcPre, const float* __restrict__ cw,
    const float* __restrict__ cb, _Float16* __restrict__ bcNat, _Float16* __restrict__ BT)
{
    __shared__ _Float16 tT[32][36];
    const int bx = blockIdx.x;
    const int ct = bx & 7, tt = (bx >> 3) & 127, b = bx >> 10;
    const int t0 = tt * 32, c0 = ct * 32;
    const int tid = threadIdx.x;
    const int tq = tid >> 3, cg = tid & 7;
    const int t = t0 + tq;
    const int ca = 1024 + c0 + cg * 4;
    const int m = b * LSEQ + t;

    float acc[4] = {cb[ca], cb[ca + 1], cb[ca + 2], cb[ca + 3]};
    #pragma unroll
    for (int j = 0; j < 4; ++j) {
        if (t - j >= 0) {
            f16x4 xv = *(const f16x4*)&xbcPre[(size_t)(m - j) * CONV_DIM + ca];
            #pragma unroll
            for (int i = 0; i < 4; ++i)
                acc[i] = fmaf((float)xv[i], cw[(ca + i) * 4 + (3 - j)], acc[i]);
        }
    }
    f16x4 nat;
    #pragma unroll
    for (int i = 0; i < 4; ++i) {
        float s = acc[i] / (1.f + expf(-acc[i]));
        nat[i] = (_Float16)s;
        tT[cg * 4 + i][tq] = nat[i];
    }
    *(f16x4*)&bcNat[(size_t)m * 256 + c0 + cg * 4] = nat;
    if (ct < 4) {   // B channels: also transposed
        __syncthreads();
        const int r = tid >> 3, g = tid & 7;
        f16x4 o = *(const f16x4*)&tT[r][g * 4];
        *(f16x4*)&BT[((size_t)b * D_STATE + c0 + r) * LSEQ + t0 + g * 4] = o;
    }
}

// ---------------- K4aA: per-chunk local state GEMM: ST[p][n] = sum_tau w_tau X[tau][p] B[tau][n] ----------------
__global__ __launch_bounds__(256) void k4aA(
    const _Float16* __restrict__ xsT, const _Float16* __restrict__ BT,
    const float* __restrict__ dtp, const float* __restrict__ ldA,
    _Float16* __restrict__ ST, float* __restrict__ Pbuf)
{
    __shared__ char smem[128 * 72 * 2 * 2 + 512];
    _Float16* sXTs = (_Float16*)smem;
    _Float16* sBT  = sXTs + 128 * 72;
    float* sW = (float*)(sBT + 128 * 72);
    _Float16* sOut = sXTs;   // reuse for repack

    const int tid = threadIdx.x;
    const int lane = tid & 63;
    const int wv = tid >> 6;
    const int quad = lane >> 4, l15 = lane & 15;
    const int c = blockIdx.x & 63;
    const int h = (blockIdx.x >> 6) & 7;
    const int b = blockIdx.x >> 9;
    const int bh = b * NHEADS + h;
    const size_t mbase = (size_t)b * LSEQ + c * QC;

    if (tid < 64) {
        size_t gi = (mbase + tid) * NHEADS + h;
        float ld = ldA[gi];
        float dtv = dtp[gi];
        float cum = ld;
        #pragma unroll
        for (int off = 1; off < 64; off <<= 1) {
            float v = __shfl_up(cum, off);
            if (tid >= off) cum += v;
        }
        float cum63 = __shfl(cum, 63);
        sW[tid] = expf(cum63 - cum) * dtv;
        if (tid == 63) Pbuf[bh * NCH + c] = expf(cum63);
    }
    __syncthreads();

    #pragma unroll
    for (int k = 0; k < 4; ++k) {
        int idx = k * 256 + tid;
        int row = idx >> 3, g = idx & 7;
        int t0 = g * 8;
        f16x8 hv = *(const f16x8*)&xsT[((size_t)b * D_INNER + h * HEADDIM + row) * LSEQ + c * QC + t0];
        f16x8 sv;
        #pragma unroll
        for (int j = 0; j < 8; ++j) sv[j] = (_Float16)((float)hv[j] * sW[t0 + j]);
        *(f16x8*)&sXTs[row * 72 + t0] = sv;
        int4 bv = *(const int4*)&BT[((size_t)b * D_STATE + row) * LSEQ + c * QC + t0];
        *(int4*)&sBT[row * 72 + t0] = bv;
    }
    __syncthreads();

    f32x4 acc[2][8];
    #pragma unroll
    for (int i = 0; i < 2; ++i)
        #pragma unroll
        for (int j = 0; j < 8; ++j) acc[i][j] = (f32x4){0.f, 0.f, 0.f, 0.f};

    #pragma unroll
    for (int kk = 0; kk < 2; ++kk) {
        f16x8 af[2];
        #pragma unroll
        for (int mi = 0; mi < 2; ++mi)
            af[mi] = *(const f16x8*)&sXTs[(wv * 32 + mi * 16 + l15) * 72 + kk * 32 + quad * 8];
        #pragma unroll
        for (int ni = 0; ni < 8; ++ni) {
            f16x8 bf_ = *(const f16x8*)&sBT[(ni * 16 + l15) * 72 + kk * 32 + quad * 8];
            #pragma unroll
            for (int mi = 0; mi < 2; ++mi)
                acc[mi][ni] = __builtin_amdgcn_mfma_f32_16x16x32_f16(af[mi], bf_, acc[mi][ni], 0, 0, 0);
        }
    }
    __syncthreads();
    #pragma unroll
    for (int mi = 0; mi < 2; ++mi)
        #pragma unroll
        for (int ni = 0; ni < 8; ++ni)
            #pragma unroll
            for (int reg = 0; reg < 4; ++reg) {
                int p = wv * 32 + mi * 16 + quad * 4 + reg;
                int n = ni * 16 + l15;
                sOut[p * 136 + n] = (_Float16)acc[mi][ni][reg];
            }
    __syncthreads();
    _Float16* stg = ST + ((size_t)bh * NCH + c) * (HEADDIM * D_STATE);
    #pragma unroll
    for (int k = 0; k < 8; ++k) {
        int idx = k * 256 + tid;
        int row = idx >> 4, g = idx & 15;
        int4 v = *(const int4*)&sOut[row * 136 + g * 8];
        *(int4*)&stg[row * 128 + g * 8] = v;
    }
}

// ---------------- K4bB: 64-chunk state prefix (in place): S_local -> s_init ----------------
__global__ __launch_bounds__(256) void k4bB(_Float16* __restrict__ ST, const float* __restrict__ Pbuf)
{
    __shared__ float sp_[NCH];
    const int bh = blockIdx.x >> 4;
    const int seg = blockIdx.x & 15;
    const int tid = threadIdx.x;
    if (tid < NCH) sp_[tid] = Pbuf[bh * NCH + tid];
    __syncthreads();
    const int e = seg * 1024 + tid * 4;
    float r0 = 0.f, r1 = 0.f, r2 = 0.f, r3 = 0.f;
    for (int c = 0; c < NCH; ++c) {
        _Float16* ptr = ST + ((size_t)bh * NCH + c) * (HEADDIM * D_STATE) + e;
        f16x4 v = *(const f16x4*)ptr;
        float f0 = (float)v[0], f1 = (float)v[1], f2 = (float)v[2], f3 = (float)v[3];
        f16x4 o; o[0] = (_Float16)r0; o[1] = (_Float16)r1; o[2] = (_Float16)r2; o[3] = (_Float16)r3;
        *(f16x4*)ptr = o;
        float P = sp_[c];
        r0 = fmaf(r0, P, f0); r1 = fmaf(r1, P, f1);
        r2 = fmaf(r2, P, f2); r3 = fmaf(r3, P, f3);
    }
}

// ---------------- K4cC: per-chunk y via SSD GEMMs ----------------
__global__ __launch_bounds__(256) void k4cC(
    const _Float16* __restrict__ bcNat, const _Float16* __restrict__ xsT,
    const _Float16* __restrict__ sinit, const float* __restrict__ dtp,
    const float* __restrict__ ldA, const float* __restrict__ Dp,
    _Float16* __restrict__ yB)
{
    __shared__ char smem[(64*136 + 64*136 + 128*72 + 4*16*72) * 2 + 640];
    _Float16* sC  = (_Float16*)smem;          // 64 x 136
    _Float16* sB  = sC + 64 * 136;            // 64 x 136
    _Float16* sXT = sB + 64 * 136;            // 128 x 72
    _Float16* sM  = sXT + 128 * 72;           // 4 waves x 16 x 72
    float* scum = (float*)(sM + 4 * 16 * 72); // 64
    float* sdt  = scum + 64;                  // 64
    _Float16* sIni = sB;                      // 128 x 136 overlays sB+sXT
    _Float16* sY  = sC;                       // 64 x 136 overlays sC

    const int tid = threadIdx.x;
    const int lane = tid & 63;
    const int wv = tid >> 6;
    const int quad = lane >> 4, l15 = lane & 15;
    const int c = blockIdx.x & 63;
    const int h = (blockIdx.x >> 6) & 7;
    const int b = blockIdx.x >> 9;
    const int bh = b * NHEADS + h;
    const size_t mbase = (size_t)b * LSEQ + c * QC;
    const float Dh = Dp[h];

    if (tid < 64) {
        size_t gi = (mbase + tid) * NHEADS + h;
        float ld = ldA[gi];
        float dtv = dtp[gi];
        float cum = ld;
        #pragma unroll
        for (int off = 1; off < 64; off <<= 1) {
            float v = __shfl_up(cum, off);
            if (tid >= off) cum += v;
        }
        scum[tid] = cum;
        sdt[tid] = dtv;
    }
    #pragma unroll
    for (int k = 0; k < 4; ++k) {
        int idx = k * 256 + tid;
        int t = idx >> 4, g = idx & 15;
        const _Float16* row = bcNat + (mbase + t) * 256;
        *(int4*)&sB[t * 136 + g * 8] = *(const int4*)&row[g * 8];
        *(int4*)&sC[t * 136 + g * 8] = *(const int4*)&row[128 + g * 8];
        int idx2 = k * 256 + tid;
        int p = idx2 >> 3, g2 = idx2 & 7;
        *(int4*)&sXT[p * 72 + g2 * 8] =
            *(const int4*)&xsT[((size_t)b * D_INNER + h * HEADDIM + p) * LSEQ + c * QC + g2 * 8];
    }
    __syncthreads();

    // G = C @ B^T
    f32x4 g[4];
    #pragma unroll
    for (int j = 0; j < 4; ++j) g[j] = (f32x4){0.f, 0.f, 0.f, 0.f};
    #pragma unroll
    for (int kk = 0; kk < 4; ++kk) {
        f16x8 af = *(const f16x8*)&sC[(wv * 16 + l15) * 136 + kk * 32 + quad * 8];
        #pragma unroll
        for (int tt = 0; tt < 4; ++tt) {
            f16x8 bf_ = *(const f16x8*)&sB[(tt * 16 + l15) * 136 + kk * 32 + quad * 8];
            g[tt] = __builtin_amdgcn_mfma_f32_16x16x32_f16(af, bf_, g[tt], 0, 0, 0);
        }
    }
    _Float16* sMw = sM + wv * 16 * 72;
    #pragma unroll
    for (int tt = 0; tt < 4; ++tt) {
        int tau = tt * 16 + l15;
        #pragma unroll
        for (int reg = 0; reg < 4; ++reg) {
            int trow = quad * 4 + reg;
            int tglob = wv * 16 + trow;
            float mval;
            if (tau > tglob) mval = 0.f;
            else if (tau == tglob) mval = g[tt][reg] * sdt[tau] + Dh;
            else mval = g[tt][reg] * expf(scum[tglob] - scum[tau]) * sdt[tau];
            sMw[trow * 72 + tau] = (_Float16)mval;
        }
    }
    asm volatile("s_waitcnt lgkmcnt(0)" ::: "memory");

    // Y1 = M @ X^T
    f32x4 y[8];
    #pragma unroll
    for (int j = 0; j < 8; ++j) y[j] = (f32x4){0.f, 0.f, 0.f, 0.f};
    #pragma unroll
    for (int kk = 0; kk < 2; ++kk) {
        f16x8 af = *(const f16x8*)&sMw[l15 * 72 + kk * 32 + quad * 8];
        #pragma unroll
        for (int pi = 0; pi < 8; ++pi) {
            f16x8 bf_ = *(const f16x8*)&sXT[(pi * 16 + l15) * 72 + kk * 32 + quad * 8];
            y[pi] = __builtin_amdgcn_mfma_f32_16x16x32_f16(af, bf_, y[pi], 0, 0, 0);
        }
    }
    __syncthreads();
    {
        const _Float16* sg = sinit + ((size_t)bh * NCH + c) * (HEADDIM * D_STATE);
        #pragma unroll
        for (int k = 0; k < 8; ++k) {
            int idx = k * 256 + tid;
            int p = idx >> 4, gg = idx & 15;
            *(int4*)&sIni[p * 136 + gg * 8] = *(const int4*)&sg[p * 128 + gg * 8];
        }
    }
    __syncthreads();
    // Y2 += (e^cum * C) @ s_init^T
    {
        float ea = expf(scum[wv * 16 + l15]);
        #pragma unroll
        for (int kk = 0; kk < 4; ++kk) {
            f16x8 cf = *(const f16x8*)&sC[(wv * 16 + l15) * 136 + kk * 32 + quad * 8];
            f16x8 af;
            #pragma unroll
            for (int j = 0; j < 8; ++j) af[j] = (_Float16)((float)cf[j] * ea);
            #pragma unroll
            for (int pi = 0; pi < 8; ++pi) {
                f16x8 bf_ = *(const f16x8*)&sIni[(pi * 16 + l15) * 136 + kk * 32 + quad * 8];
                y[pi] = __builtin_amdgcn_mfma_f32_16x16x32_f16(af, bf_, y[pi], 0, 0, 0);
            }
        }
    }
    __syncthreads();
    #pragma unroll
    for (int pi = 0; pi < 8; ++pi)
        #pragma unroll
        for (int reg = 0; reg < 4; ++reg) {
            int trow = wv * 16 + quad * 4 + reg;
            int p = pi * 16 + l15;
            sY[trow * 136 + p] = (_Float16)y[pi][reg];
        }
    __syncthreads();
    #pragma unroll
    for (int k = 0; k < 4; ++k) {
        int idx = k * 256 + tid;
        int t = idx >> 4, gg = idx & 15;
        int4 v = *(const int4*)&sY[t * 136 + gg * 8];
        *(int4*)&yB[(mbase + t) * D_INNER + h * HEADDIM + gg * 8] = v;
    }
}

// ---------------- K5: y *= silu(z); RMSNorm * norm_w -> bf16 (in place over yB) ----------------
__global__ __launch_bounds__(256) void k5_norm(
    const _Float16* __restrict__ yB, const _Float16* __restrict__ zh,
    const float* __restrict__ nw, ushort* __restrict__ ybB)
{
    const int m = blockIdx.x;
    const int tid = threadIdx.x;
    const size_t off = (size_t)m * D_INNER + tid * 4;
    f16x4 yv = *(const f16x4*)&yB[off];
    f16x4 zv = *(const f16x4*)&zh[off];
    float4 gv;
    {
        float z0 = (float)zv[0], z1 = (float)zv[1], z2 = (float)zv[2], z3 = (float)zv[3];
        gv.x = (float)yv[0] * (z0 / (1.f + expf(-z0)));
        gv.y = (float)yv[1] * (z1 / (1.f + expf(-z1)));
        gv.z = (float)yv[2] * (z2 / (1.f + expf(-z2)));
        gv.w = (float)yv[3] * (z3 / (1.f + expf(-z3)));
    }
    float ss = gv.x*gv.x + gv.y*gv.y + gv.z*gv.z + gv.w*gv.w;
    #pragma unroll
    for (int mask = 1; mask <= 32; mask <<= 1) ss += __shfl_xor(ss, mask);
    __shared__ float red[4];
    if ((tid & 63) == 0) red[tid >> 6] = ss;
    __syncthreads();
    float tot = red[0] + red[1] + red[2] + red[3];
    float scale = rsqrtf(tot * (1.f / 1024.f) + 1e-5f);
    float4 w4 = *(const float4*)(nw + tid * 4);
    ushort4 ob;
    ob.x = f2bf(gv.x * scale * w4.x);
    ob.y = f2bf(gv.y * scale * w4.y);
    ob.z = f2bf(gv.z * scale * w4.z);
    ob.w = f2bf(gv.w * scale * w4.w);
    *(ushort4*)(ybB + off) = ob;
}

// ---------------- K6: out_proj GEMM bf16 MFMA + residual, global_load_lds staging ----------------
__global__ __launch_bounds__(256) void k6_mfma(
    const ushort* __restrict__ A, const ushort* __restrict__ B,
    const float* __restrict__ x, float* __restrict__ out)
{
    __shared__ ushort sA[128 * 32];
    __shared__ ushort sB[128 * 32];
    const int tid = threadIdx.x;
    const int lane = tid & 63;
    const int wv = tid >> 6;
    const int wm = (wv & 1) * 64, wn = (wv >> 1) * 64;
    const int m0 = blockIdx.x * 128;
    const int n0 = blockIdx.y * 128;

    f32x4 acc[4][4];
    #pragma unroll
    for (int i = 0; i < 4; ++i)
        #pragma unroll
        for (int j = 0; j < 4; ++j) acc[i][j] = (f32x4){0.f, 0.f, 0.f, 0.f};

    const int r0 = tid >> 2, c0 = tid & 3, k80 = c0 ^ ((r0 >> 1) & 3);
    const int s1_ = tid + 256;
    const int r1 = s1_ >> 2, c1 = s1_ & 3, k81 = c1 ^ ((r1 >> 1) & 3);
    const int quad = lane >> 4, col = lane & 15;
    ushort* lA0 = sA + (size_t)(wv * 64) * 8;
    ushort* lA1 = sA + (size_t)(256 + wv * 64) * 8;
    ushort* lB0 = sB + (size_t)(wv * 64) * 8;
    ushort* lB1 = sB + (size_t)(256 + wv * 64) * 8;

    for (int kb = 0; kb < D_INNER; kb += 32) {
        gload_lds16(A + (size_t)(m0 + r0) * D_INNER + kb + k80 * 8, lA0);
        gload_lds16(A + (size_t)(m0 + r1) * D_INNER + kb + k81 * 8, lA1);
        gload_lds16(B + (size_t)(n0 + r0) * D_INNER + kb + k80 * 8, lB0);
        gload_lds16(B + (size_t)(n0 + r1) * D_INNER + kb + k81 * 8, lB1);
        __syncthreads();
        bf16x8 af[4], bf_[4];
        #pragma unroll
        for (int mi = 0; mi < 4; ++mi) {
            int m = wm + mi * 16 + col;
            int ch = quad ^ ((m >> 1) & 3);
            af[mi] = *(const bf16x8*)&sA[m * 32 + ch * 8];
        }
        #pragma unroll
        for (int ni = 0; ni < 4; ++ni) {
            int n = wn + ni * 16 + col;
            int ch = quad ^ ((n >> 1) & 3);
            bf_[ni] = *(const bf16x8*)&sB[n * 32 + ch * 8];
        }
        #pragma unroll
        for (int mi = 0; mi < 4; ++mi)
            #pragma unroll
            for (int ni = 0; ni < 4; ++ni)
                acc[mi][ni] = __builtin_amdgcn_mfma_f32_16x16x32_bf16(af[mi], bf_[ni], acc[mi][ni], 0, 0, 0);
        __syncthreads();
    }

    #pragma unroll
    for (int mi = 0; mi < 4; ++mi) {
        #pragma unroll
        for (int ni = 0; ni < 4; ++ni) {
            int mm = n0 + wn + ni * 16 + col;
            int b = mm >> 12, l = mm & 4095;
            #pragma unroll
            for (int reg = 0; reg < 4; ++reg) {
                int d = m0 + wm + mi * 16 + quad * 4 + reg;
                size_t o = ((size_t)(b * DIMC + d) << 12) + l;
                out[o] = acc[mi][ni][reg] + x[o];
            }
        }
    }
}

extern "C" void kernel_launch(void* const* d_in, const int* in_sizes, int n_in,
                              void* d_out, int out_size, void* d_ws, size_t ws_size,
                              hipStream_t stream) {
    const float* x          = (const float*)d_in[0];
    const float* in_proj_w  = (const float*)d_in[1];
    const float* conv_w     = (const float*)d_in[2];
    const float* conv_b     = (const float*)d_in[3];
    const float* dt_bias    = (const float*)d_in[4];
    const float* A_log      = (const float*)d_in[5];
    const float* D_param    = (const float*)d_in[6];
    const float* norm_w     = (const float*)d_in[7];
    const float* out_proj_w = (const float*)d_in[8];
    float* out = (float*)d_out;

    float* ws = (float*)d_ws;
    float* zbuf = ws;                                      // region A: 16,777,216 f32
    _Float16* zh = (_Float16*)zbuf;                        // z stored f16 (33.5 MB)
    float* regB = zbuf + (size_t)16777216;
    _Float16* xbcPre = (_Float16*)regB;                    // 16384x1280 f16
    _Float16* yB     = (_Float16*)regB;                    // 16384x1024 f16 (after k3)
    float* dtb  = regB + (size_t)10485760;
    float* dtp  = dtb + 131072;
    float* ldA  = dtp + 131072;
    float* Pbuf = ldA + 131072;                            // 2048
    float* regD = Pbuf + 2048;
    ushort* xT_k1 = (ushort*)regD;                         // 16384x512 bf16
    ushort* Wb    = xT_k1 + (size_t)BLTOT * DIMC;          // 2432x512 bf16
    _Float16* ST  = (_Float16*)regD;                       // 32x64x128x128 f16 (after k1)
    float* regE = regD + (size_t)16777216;
    _Float16* xsT   = (_Float16*)regE;                     // 4x1024x4096 f16
    _Float16* BT    = xsT + (size_t)BSZ * D_INNER * LSEQ;  // 4x128x4096 f16
    _Float16* bcNat = BT + (size_t)BSZ * D_STATE * LSEQ;   // 16384x256 f16
    ushort* woutB = (ushort*)zbuf;                         // after k5

    k0a_xT<<<dim3(8192), dim3(256), 0, stream>>>(x, xT_k1);
    k0b_wb<<<dim3(NPAD * DIMC / 1024), dim3(256), 0, stream>>>(in_proj_w, Wb);
    k1_mfma<<<dim3(128, 19), dim3(256), 0, stream>>>(xT_k1, Wb, zh, xbcPre, dtb);
    k2_dt<<<dim3(512), dim3(256), 0, stream>>>(dtb, dt_bias, A_log, dtp, ldA);
    k3x<<<dim3(16384), dim3(256), 0, stream>>>(xbcPre, conv_w, conv_b, xsT);
    k3bc<<<dim3(4096), dim3(256), 0, stream>>>(xbcPre, conv_w, conv_b, bcNat, BT);
    k4aA<<<dim3(2048), dim3(256), 0, stream>>>(xsT, BT, dtp, ldA, ST, Pbuf);
    k4bB<<<dim3(512), dim3(256), 0, stream>>>(ST, Pbuf);
    k4cC<<<dim3(2048), dim3(256), 0, stream>>>(bcNat, xsT, ST, dtp, ldA, D_param, yB);
    k5_norm<<<dim3(BLTOT), dim3(256), 0, stream>>>(yB, zh, norm_w, (ushort*)yB);
    k0c_wout<<<dim3(512), dim3(256), 0, stream>>>(out_proj_w, woutB);
    k6_mfma<<<dim3(4, 128), dim3(256), 0, stream>>>(woutB, (ushort*)yB, x, out);
}